// Round 3
// baseline (105961.011 us; speedup 1.0000x reference)
//
#include <hip/hip_runtime.h>
#include <cstdint>

// Problem constants (from reference setup_inputs / signature)
static constexpr int C          = 5;
static constexpr int MAX_POINTS = 10;
static constexpr int MAX_VOXELS = 160000;
static constexpr int HASH_BITS  = 19;            // 524288 slots, ~30% load at 160k voxels
static constexpr int HSIZE      = 1 << HASH_BITS;
static constexpr int EMPTY_SLOT = 0x7F7F7F7F;
static constexpr int BLK        = 256;
static constexpr int MAX_PROBE  = 4096;          // bound on linear-probe cluster walk

// Output layout (float32, concatenated in reference return order)
static constexpr int VOX_OFF = 0;                                    // 160000*10*5
static constexpr int CO_OFF  = MAX_VOXELS * MAX_POINTS * C;          // 8,000,000
static constexpr int NPV_OFF = CO_OFF + MAX_VOXELS * 3;              // 8,480,000
static constexpr int VN_OFF  = NPV_OFF + MAX_VOXELS;                 // 8,640,000

__device__ __forceinline__ uint32_t hash_key(int l) {
    return ((uint32_t)l * 2654435761u) >> (32 - HASH_BITS);
}

// K0: init all workspace arrays (no hipMemsetAsync -> graph-capture safe).
__global__ void k_init(int* __restrict__ key, int* __restrict__ minidx,
                       int* __restrict__ voxid, int* __restrict__ cnt,
                       int* __restrict__ voxlin, int* __restrict__ slotarr) {
    int t = blockIdx.x * BLK + threadIdx.x;
    if (t < HSIZE) { key[t] = -1; minidx[t] = EMPTY_SLOT; voxid[t] = -1; }
    if (t < MAX_VOXELS) { cnt[t] = 0; voxlin[t] = -1; }
    if (t < MAX_VOXELS * MAX_POINTS) slotarr[t] = EMPTY_SLOT;
}

// K1: quantize points, insert key into hash table, atomicMin head index.
__global__ void k_quantize(const float* __restrict__ pts,
                           const float* __restrict__ vsz,
                           const float* __restrict__ crg,
                           int* __restrict__ slotidx,
                           int* __restrict__ key, int* __restrict__ minidx,
                           int NP) {
    int i = blockIdx.x * BLK + threadIdx.x;
    if (i >= NP) return;
    float vx = vsz[0], vy = vsz[1], vz = vsz[2];
    float x0 = crg[0], y0 = crg[1], z0 = crg[2];
    int gx = (int)rintf((crg[3] - x0) / vx);
    int gy = (int)rintf((crg[4] - y0) / vy);
    int gz = (int)rintf((crg[5] - z0) / vz);
    float px = pts[i * C + 0], py = pts[i * C + 1], pz = pts[i * C + 2];
    int cx = (int)floorf((px - x0) / vx);
    int cy = (int)floorf((py - y0) / vy);
    int cz = (int)floorf((pz - z0) / vz);
    bool valid = (cx >= 0) & (cx < gx) & (cy >= 0) & (cy < gy) & (cz >= 0) & (cz < gz);
    if (!valid) { slotidx[i] = -1; return; }
    int l = (cx * gy + cy) * gz + cz;
    uint32_t h = hash_key(l) & (HSIZE - 1);
    int slot = -1;
    for (int probe = 0; probe < MAX_PROBE; probe++) {
        int k = atomicCAS(&key[h], -1, l);
        if (k == -1 || k == l) { slot = (int)h; break; }
        h = (h + 1) & (HSIZE - 1);
    }
    slotidx[i] = slot;
    if (slot >= 0) atomicMin(&minidx[slot], i);
}

// K2: head flags (point i is head iff it is the min-index point of its voxel)
// reduced to per-block sums.
__global__ void k_blocksum(const int* __restrict__ slotidx,
                           const int* __restrict__ minidx,
                           int* __restrict__ bsum, int NP) {
    __shared__ int s[BLK];
    int i = blockIdx.x * BLK + threadIdx.x;
    int f = 0;
    if (i < NP) {
        int sl = slotidx[i];
        if (sl >= 0) f = (minidx[sl] == i) ? 1 : 0;
    }
    s[threadIdx.x] = f;
    __syncthreads();
    for (int st = BLK / 2; st > 0; st >>= 1) {
        if (threadIdx.x < st) s[threadIdx.x] += s[threadIdx.x + st];
        __syncthreads();
    }
    if (threadIdx.x == 0) bsum[blockIdx.x] = s[0];
}

// K3: single-block (256-thread) exclusive scan of block sums; writes voxel_num.
__global__ void k_scan(int* __restrict__ bsum, int nb, float* __restrict__ out_vnum) {
    __shared__ int s[BLK];
    __shared__ int carry;
    int tid = threadIdx.x;
    if (tid == 0) carry = 0;
    __syncthreads();
    for (int base = 0; base < nb; base += BLK) {
        int i = base + tid;
        int v = (i < nb) ? bsum[i] : 0;
        s[tid] = v;
        __syncthreads();
        for (int d = 1; d < BLK; d <<= 1) {
            int t = (tid >= d) ? s[tid - d] : 0;
            __syncthreads();
            s[tid] += t;
            __syncthreads();
        }
        int incl = s[tid];
        int c = carry;
        if (i < nb) bsum[i] = c + incl - v;   // exclusive offset
        __syncthreads();
        if (tid == BLK - 1) carry = c + incl; // chunk total
        __syncthreads();
    }
    if (tid == 0) {
        int t = carry;
        out_vnum[0] = (float)(t < MAX_VOXELS ? t : MAX_VOXELS);
    }
}

// K4: assign voxel ids to heads (rank = global exclusive prefix of head flags).
__global__ void k_rank(const int* __restrict__ slotidx, const int* __restrict__ minidx,
                       const int* __restrict__ key, const int* __restrict__ bsum,
                       int* __restrict__ voxid, int* __restrict__ voxlin, int NP) {
    __shared__ int s[BLK];
    int i = blockIdx.x * BLK + threadIdx.x;
    int sl = (i < NP) ? slotidx[i] : -1;
    int f = (sl >= 0 && minidx[sl] == i) ? 1 : 0;
    s[threadIdx.x] = f;
    __syncthreads();
    for (int d = 1; d < BLK; d <<= 1) {
        int t = (threadIdx.x >= d) ? s[threadIdx.x - d] : 0;
        __syncthreads();
        s[threadIdx.x] += t;
        __syncthreads();
    }
    if (f) {
        int rank = bsum[blockIdx.x] + s[threadIdx.x] - 1;
        if (rank >= 0 && rank < MAX_VOXELS) {
            voxid[sl] = rank;
            voxlin[rank] = key[sl];
        }
    }
}

// K5: per-voxel counts + sorted 10-smallest point indices via atomicMin waterfall.
__global__ void k_slots(const int* __restrict__ slotidx, const int* __restrict__ voxid,
                        int* __restrict__ cnt, int* __restrict__ slotarr, int NP) {
    int i = blockIdx.x * BLK + threadIdx.x;
    if (i >= NP) return;
    int sl = slotidx[i];
    if (sl < 0) return;
    int v = voxid[sl];
    if (v < 0 || v >= MAX_VOXELS) return;
    atomicAdd(&cnt[v], 1);
    int val = i;
    int base = v * MAX_POINTS;
    #pragma unroll
    for (int k = 0; k < MAX_POINTS; k++) {
        int old = atomicMin(&slotarr[base + k], val);
        if (old == EMPTY_SLOT) break;       // landed in empty slot, done
        val = (old > val) ? old : val;      // carry displaced (larger) value down
    }
}

// K6: write ALL outputs (d_out is poisoned before every timed replay).
__global__ void k_write(const float* __restrict__ pts,
                        const float* __restrict__ vsz,
                        const float* __restrict__ crg,
                        const int* __restrict__ slotarr, const int* __restrict__ voxlin,
                        const int* __restrict__ cnt, float* __restrict__ out, int NP) {
    const int TOTV = MAX_VOXELS * MAX_POINTS;
    int t = blockIdx.x * BLK + threadIdx.x;
    if (t < TOTV) {
        int idx = slotarr[t];
        float o0 = 0.f, o1 = 0.f, o2 = 0.f, o3 = 0.f, o4 = 0.f;
        if (idx != EMPTY_SLOT && idx >= 0 && idx < NP) {
            const float* p = pts + idx * C;
            o0 = p[0]; o1 = p[1]; o2 = p[2]; o3 = p[3]; o4 = p[4];
        }
        float* dst = out + VOX_OFF + t * C;
        dst[0] = o0; dst[1] = o1; dst[2] = o2; dst[3] = o3; dst[4] = o4;
    } else if (t < TOTV + MAX_VOXELS) {
        int v = t - TOTV;
        int l = voxlin[v];
        float a = 0.f, b = 0.f, c2 = 0.f;
        if (l >= 0) {
            int gy = (int)rintf((crg[4] - crg[1]) / vsz[1]);
            int gz = (int)rintf((crg[5] - crg[2]) / vsz[2]);
            int cz = l % gz;
            int r  = l / gz;
            int cy = r % gy;
            int cx = r / gy;
            a = (float)cz; b = (float)cy; c2 = (float)cx;   // coors row = (z,y,x)
        }
        out[CO_OFF + v * 3 + 0] = a;
        out[CO_OFF + v * 3 + 1] = b;
        out[CO_OFF + v * 3 + 2] = c2;
        int cn = cnt[v];
        if (cn > MAX_POINTS) cn = MAX_POINTS;
        out[NPV_OFF + v] = (float)cn;
    }
}

extern "C" void kernel_launch(void* const* d_in, const int* in_sizes, int n_in,
                              void* d_out, int out_size, void* d_ws, size_t ws_size,
                              hipStream_t stream) {
    if (!d_out || !d_ws || n_in < 3) return;
    const float* pts = (const float*)d_in[0];
    const float* vsz = (const float*)d_in[1];
    const float* crg = (const float*)d_in[2];
    if (!pts || !vsz || !crg) return;
    const int NP = in_sizes[0] / C;
    if (NP <= 0) return;
    const int nb = (NP + BLK - 1) / BLK;

    // Workspace budget check (graceful bail -> visible absmax failure, not a crash)
    size_t need = ((size_t)NP + (size_t)nb + 3ull * HSIZE + 2ull * MAX_VOXELS
                   + (size_t)MAX_VOXELS * MAX_POINTS) * 4ull;
    if (ws_size < need) return;
    if ((size_t)out_size < (size_t)VN_OFF + 1) return;

    int* w = (int*)d_ws;
    int* slotidx = w; w += NP;
    int* bsum    = w; w += nb;
    int* key     = w; w += HSIZE;
    int* minidx  = w; w += HSIZE;
    int* voxid   = w; w += HSIZE;
    int* cnt     = w; w += MAX_VOXELS;
    int* voxlin  = w; w += MAX_VOXELS;
    int* slotarr = w; w += MAX_VOXELS * MAX_POINTS;

    float* out = (float*)d_out;

    const int init_n = MAX_VOXELS * MAX_POINTS;   // largest array; covers HSIZE too
    k_init<<<(init_n + BLK - 1) / BLK, BLK, 0, stream>>>(key, minidx, voxid, cnt, voxlin, slotarr);
    k_quantize<<<nb, BLK, 0, stream>>>(pts, vsz, crg, slotidx, key, minidx, NP);
    k_blocksum<<<nb, BLK, 0, stream>>>(slotidx, minidx, bsum, NP);
    k_scan<<<1, BLK, 0, stream>>>(bsum, nb, out + VN_OFF);
    k_rank<<<nb, BLK, 0, stream>>>(slotidx, minidx, key, bsum, voxid, voxlin, NP);
    k_slots<<<nb, BLK, 0, stream>>>(slotidx, voxid, cnt, slotarr, NP);

    const int tot = MAX_VOXELS * MAX_POINTS + MAX_VOXELS;
    k_write<<<(tot + BLK - 1) / BLK, BLK, 0, stream>>>(pts, vsz, crg, slotarr, voxlin, cnt, out, NP);
}

// Round 4
// 104265.466 us; speedup vs baseline: 1.0163x; 1.0163x over previous
//
#include <hip/hip_runtime.h>
#include <cstdint>

// Problem constants (from reference setup_inputs / signature)
static constexpr int C          = 5;
static constexpr int MAX_POINTS = 10;
static constexpr int MAX_VOXELS = 160000;
static constexpr int HASH_BITS  = 19;            // 524288 slots, ~30% load at 160k voxels
static constexpr int HSIZE      = 1 << HASH_BITS;
static constexpr int EMPTY_SLOT = 0x7F7F7F7F;
static constexpr int BLK        = 256;
static constexpr int MAX_PROBE  = 4096;          // correctness guard; never hit w/ avalanche hash

// Output layout (float32, concatenated in reference return order)
static constexpr int VOX_OFF = 0;                                    // 160000*10*5
static constexpr int CO_OFF  = MAX_VOXELS * MAX_POINTS * C;          // 8,000,000
static constexpr int NPV_OFF = CO_OFF + MAX_VOXELS * 3;              // 8,480,000
static constexpr int VN_OFF  = NPV_OFF + MAX_VOXELS;                 // 8,640,000

// Murmur3 finalizer — full avalanche. The previous golden-ratio multiplicative
// hash resonated with the key lattice {1,40,57600} (Fibonacci vectors, e.g.
// Δl=10946 → 12 slots apart), collapsing the table into ~1000-slot clusters
// (163 GB of CAS write traffic, 134 ms). Avalanche destroys lattice structure.
__device__ __forceinline__ uint32_t hash_key(uint32_t x) {
    x ^= x >> 16; x *= 0x85ebca6bu;
    x ^= x >> 13; x *= 0xc2b2ae35u;
    x ^= x >> 16;
    return x & (HSIZE - 1);
}

// K0: init all workspace arrays (no hipMemsetAsync -> graph-capture safe).
__global__ void k_init(int* __restrict__ key, int* __restrict__ minidx,
                       int* __restrict__ voxid, int* __restrict__ cnt,
                       int* __restrict__ voxlin, int* __restrict__ slotarr) {
    int t = blockIdx.x * BLK + threadIdx.x;
    if (t < HSIZE) { key[t] = -1; minidx[t] = EMPTY_SLOT; voxid[t] = -1; }
    if (t < MAX_VOXELS) { cnt[t] = 0; voxlin[t] = -1; }
    if (t < MAX_VOXELS * MAX_POINTS) slotarr[t] = EMPTY_SLOT;
}

// K1: quantize points, insert key into hash table, atomicMin head index.
__global__ void k_quantize(const float* __restrict__ pts,
                           const float* __restrict__ vsz,
                           const float* __restrict__ crg,
                           int* __restrict__ slotidx,
                           int* __restrict__ key, int* __restrict__ minidx,
                           int NP) {
    int i = blockIdx.x * BLK + threadIdx.x;
    if (i >= NP) return;
    float vx = vsz[0], vy = vsz[1], vz = vsz[2];
    float x0 = crg[0], y0 = crg[1], z0 = crg[2];
    int gx = (int)rintf((crg[3] - x0) / vx);
    int gy = (int)rintf((crg[4] - y0) / vy);
    int gz = (int)rintf((crg[5] - z0) / vz);
    float px = pts[i * C + 0], py = pts[i * C + 1], pz = pts[i * C + 2];
    int cx = (int)floorf((px - x0) / vx);
    int cy = (int)floorf((py - y0) / vy);
    int cz = (int)floorf((pz - z0) / vz);
    bool valid = (cx >= 0) & (cx < gx) & (cy >= 0) & (cy < gy) & (cz >= 0) & (cz < gz);
    if (!valid) { slotidx[i] = -1; return; }
    int l = (cx * gy + cy) * gz + cz;
    uint32_t h = hash_key((uint32_t)l);
    int slot = -1;
    for (int probe = 0; probe < MAX_PROBE; probe++) {
        int k = atomicCAS(&key[h], -1, l);
        if (k == -1 || k == l) { slot = (int)h; break; }
        h = (h + 1) & (HSIZE - 1);
    }
    slotidx[i] = slot;
    if (slot >= 0) atomicMin(&minidx[slot], i);
}

// K2: head flags (point i is head iff it is the min-index point of its voxel)
// reduced to per-block sums.
__global__ void k_blocksum(const int* __restrict__ slotidx,
                           const int* __restrict__ minidx,
                           int* __restrict__ bsum, int NP) {
    __shared__ int s[BLK];
    int i = blockIdx.x * BLK + threadIdx.x;
    int f = 0;
    if (i < NP) {
        int sl = slotidx[i];
        if (sl >= 0) f = (minidx[sl] == i) ? 1 : 0;
    }
    s[threadIdx.x] = f;
    __syncthreads();
    for (int st = BLK / 2; st > 0; st >>= 1) {
        if (threadIdx.x < st) s[threadIdx.x] += s[threadIdx.x + st];
        __syncthreads();
    }
    if (threadIdx.x == 0) bsum[blockIdx.x] = s[0];
}

// K3: single-block (256-thread) exclusive scan of block sums; writes voxel_num.
__global__ void k_scan(int* __restrict__ bsum, int nb, float* __restrict__ out_vnum) {
    __shared__ int s[BLK];
    __shared__ int carry;
    int tid = threadIdx.x;
    if (tid == 0) carry = 0;
    __syncthreads();
    for (int base = 0; base < nb; base += BLK) {
        int i = base + tid;
        int v = (i < nb) ? bsum[i] : 0;
        s[tid] = v;
        __syncthreads();
        for (int d = 1; d < BLK; d <<= 1) {
            int t = (tid >= d) ? s[tid - d] : 0;
            __syncthreads();
            s[tid] += t;
            __syncthreads();
        }
        int incl = s[tid];
        int c = carry;
        if (i < nb) bsum[i] = c + incl - v;   // exclusive offset
        __syncthreads();
        if (tid == BLK - 1) carry = c + incl; // chunk total
        __syncthreads();
    }
    if (tid == 0) {
        int t = carry;
        out_vnum[0] = (float)(t < MAX_VOXELS ? t : MAX_VOXELS);
    }
}

// K4: assign voxel ids to heads (rank = global exclusive prefix of head flags).
__global__ void k_rank(const int* __restrict__ slotidx, const int* __restrict__ minidx,
                       const int* __restrict__ key, const int* __restrict__ bsum,
                       int* __restrict__ voxid, int* __restrict__ voxlin, int NP) {
    __shared__ int s[BLK];
    int i = blockIdx.x * BLK + threadIdx.x;
    int sl = (i < NP) ? slotidx[i] : -1;
    int f = (sl >= 0 && minidx[sl] == i) ? 1 : 0;
    s[threadIdx.x] = f;
    __syncthreads();
    for (int d = 1; d < BLK; d <<= 1) {
        int t = (threadIdx.x >= d) ? s[threadIdx.x - d] : 0;
        __syncthreads();
        s[threadIdx.x] += t;
        __syncthreads();
    }
    if (f) {
        int rank = bsum[blockIdx.x] + s[threadIdx.x] - 1;
        if (rank >= 0 && rank < MAX_VOXELS) {
            voxid[sl] = rank;
            voxlin[rank] = key[sl];
        }
    }
}

// K5: per-voxel counts + sorted 10-smallest point indices via atomicMin waterfall.
__global__ void k_slots(const int* __restrict__ slotidx, const int* __restrict__ voxid,
                        int* __restrict__ cnt, int* __restrict__ slotarr, int NP) {
    int i = blockIdx.x * BLK + threadIdx.x;
    if (i >= NP) return;
    int sl = slotidx[i];
    if (sl < 0) return;
    int v = voxid[sl];
    if (v < 0 || v >= MAX_VOXELS) return;
    atomicAdd(&cnt[v], 1);
    int val = i;
    int base = v * MAX_POINTS;
    #pragma unroll
    for (int k = 0; k < MAX_POINTS; k++) {
        int old = atomicMin(&slotarr[base + k], val);
        if (old == EMPTY_SLOT) break;       // landed in empty slot, done
        val = (old > val) ? old : val;      // carry displaced (larger) value down
    }
}

// K6: write ALL outputs (d_out is poisoned before every timed replay).
__global__ void k_write(const float* __restrict__ pts,
                        const float* __restrict__ vsz,
                        const float* __restrict__ crg,
                        const int* __restrict__ slotarr, const int* __restrict__ voxlin,
                        const int* __restrict__ cnt, float* __restrict__ out, int NP) {
    const int TOTV = MAX_VOXELS * MAX_POINTS;
    int t = blockIdx.x * BLK + threadIdx.x;
    if (t < TOTV) {
        int idx = slotarr[t];
        float o0 = 0.f, o1 = 0.f, o2 = 0.f, o3 = 0.f, o4 = 0.f;
        if (idx != EMPTY_SLOT && idx >= 0 && idx < NP) {
            const float* p = pts + idx * C;
            o0 = p[0]; o1 = p[1]; o2 = p[2]; o3 = p[3]; o4 = p[4];
        }
        float* dst = out + VOX_OFF + t * C;
        dst[0] = o0; dst[1] = o1; dst[2] = o2; dst[3] = o3; dst[4] = o4;
    } else if (t < TOTV + MAX_VOXELS) {
        int v = t - TOTV;
        int l = voxlin[v];
        float a = 0.f, b = 0.f, c2 = 0.f;
        if (l >= 0) {
            int gy = (int)rintf((crg[4] - crg[1]) / vsz[1]);
            int gz = (int)rintf((crg[5] - crg[2]) / vsz[2]);
            int cz = l % gz;
            int r  = l / gz;
            int cy = r % gy;
            int cx = r / gy;
            a = (float)cz; b = (float)cy; c2 = (float)cx;   // coors row = (z,y,x)
        }
        out[CO_OFF + v * 3 + 0] = a;
        out[CO_OFF + v * 3 + 1] = b;
        out[CO_OFF + v * 3 + 2] = c2;
        int cn = cnt[v];
        if (cn > MAX_POINTS) cn = MAX_POINTS;
        out[NPV_OFF + v] = (float)cn;
    }
}

extern "C" void kernel_launch(void* const* d_in, const int* in_sizes, int n_in,
                              void* d_out, int out_size, void* d_ws, size_t ws_size,
                              hipStream_t stream) {
    if (!d_out || !d_ws || n_in < 3) return;
    const float* pts = (const float*)d_in[0];
    const float* vsz = (const float*)d_in[1];
    const float* crg = (const float*)d_in[2];
    if (!pts || !vsz || !crg) return;
    const int NP = in_sizes[0] / C;
    if (NP <= 0) return;
    const int nb = (NP + BLK - 1) / BLK;

    // Workspace budget check (graceful bail -> visible absmax failure, not a crash)
    size_t need = ((size_t)NP + (size_t)nb + 3ull * HSIZE + 2ull * MAX_VOXELS
                   + (size_t)MAX_VOXELS * MAX_POINTS) * 4ull;
    if (ws_size < need) return;
    if ((size_t)out_size < (size_t)VN_OFF + 1) return;

    int* w = (int*)d_ws;
    int* slotidx = w; w += NP;
    int* bsum    = w; w += nb;
    int* key     = w; w += HSIZE;
    int* minidx  = w; w += HSIZE;
    int* voxid   = w; w += HSIZE;
    int* cnt     = w; w += MAX_VOXELS;
    int* voxlin  = w; w += MAX_VOXELS;
    int* slotarr = w; w += MAX_VOXELS * MAX_POINTS;

    float* out = (float*)d_out;

    const int init_n = MAX_VOXELS * MAX_POINTS;   // largest array; covers HSIZE too
    k_init<<<(init_n + BLK - 1) / BLK, BLK, 0, stream>>>(key, minidx, voxid, cnt, voxlin, slotarr);
    k_quantize<<<nb, BLK, 0, stream>>>(pts, vsz, crg, slotidx, key, minidx, NP);
    k_blocksum<<<nb, BLK, 0, stream>>>(slotidx, minidx, bsum, NP);
    k_scan<<<1, BLK, 0, stream>>>(bsum, nb, out + VN_OFF);
    k_rank<<<nb, BLK, 0, stream>>>(slotidx, minidx, key, bsum, voxid, voxlin, NP);
    k_slots<<<nb, BLK, 0, stream>>>(slotidx, voxid, cnt, slotarr, NP);

    const int tot = MAX_VOXELS * MAX_POINTS + MAX_VOXELS;
    k_write<<<(tot + BLK - 1) / BLK, BLK, 0, stream>>>(pts, vsz, crg, slotarr, voxlin, cnt, out, NP);
}

// Round 5
// 21805.724 us; speedup vs baseline: 4.8593x; 4.7816x over previous
//
#include <hip/hip_runtime.h>
#include <cstdint>

// Problem constants (from reference setup_inputs / signature)
static constexpr int C          = 5;
static constexpr int MAX_POINTS = 10;
static constexpr int MAX_VOXELS = 160000;
static constexpr int HASH_BITS  = 19;            // 524288 slots, ~30% load at 160k voxels
static constexpr int HSIZE      = 1 << HASH_BITS;
static constexpr int EMPTY_SLOT = 0x7F7F7F7F;
static constexpr int BLK        = 256;
static constexpr int MAX_PROBE  = 8192;          // guard only; double-hashing never gets close

// Output layout (float32, concatenated in reference return order)
static constexpr int VOX_OFF = 0;                                    // 160000*10*5
static constexpr int CO_OFF  = MAX_VOXELS * MAX_POINTS * C;          // 8,000,000
static constexpr int NPV_OFF = CO_OFF + MAX_VOXELS * 3;              // 8,480,000
static constexpr int VN_OFF  = NPV_OFF + MAX_VOXELS;                 // 8,640,000

// murmur3 fmix32 — full avalanche.
__device__ __forceinline__ uint32_t mix32(uint32_t x) {
    x ^= x >> 16; x *= 0x85ebca6bu;
    x ^= x >> 13; x *= 0xc2b2ae35u;
    x ^= x >> 16;
    return x;
}

// K0: init all workspace arrays (no hipMemsetAsync -> graph-capture safe).
__global__ void k_init_v2(int* __restrict__ key, int* __restrict__ minidx,
                          int* __restrict__ voxid, int* __restrict__ cnt,
                          int* __restrict__ voxlin, int* __restrict__ slotarr) {
    int t = blockIdx.x * BLK + threadIdx.x;
    if (t < HSIZE) { key[t] = -1; minidx[t] = EMPTY_SLOT; voxid[t] = -1; }
    if (t < MAX_VOXELS) { cnt[t] = 0; voxlin[t] = -1; }
    if (t < MAX_VOXELS * MAX_POINTS) slotarr[t] = EMPTY_SLOT;
}

// K1: quantize points; find-or-insert voxel key via double-hashed open addressing.
// Read-before-CAS: key[] transitions -1 -> l exactly once, so a plain load that
// returns l is final; only (possibly stale) -1 / mismatch falls through to CAS.
__global__ void k_quantize_v2(const float* __restrict__ pts,
                              const float* __restrict__ vsz,
                              const float* __restrict__ crg,
                              int* __restrict__ slotidx,
                              int* __restrict__ key, int* __restrict__ minidx,
                              int NP) {
    int i = blockIdx.x * BLK + threadIdx.x;
    if (i >= NP) return;
    float vx = vsz[0], vy = vsz[1], vz = vsz[2];
    float x0 = crg[0], y0 = crg[1], z0 = crg[2];
    int gx = (int)rintf((crg[3] - x0) / vx);
    int gy = (int)rintf((crg[4] - y0) / vy);
    int gz = (int)rintf((crg[5] - z0) / vz);
    float px = pts[i * C + 0], py = pts[i * C + 1], pz = pts[i * C + 2];
    int cx = (int)floorf((px - x0) / vx);
    int cy = (int)floorf((py - y0) / vy);
    int cz = (int)floorf((pz - z0) / vz);
    bool valid = (cx >= 0) & (cx < gx) & (cy >= 0) & (cy < gy) & (cz >= 0) & (cz < gz);
    if (!valid) { slotidx[i] = -1; return; }
    int l = (cx * gy + cy) * gz + cz;
    uint32_t hv = mix32((uint32_t)l);
    uint32_t h    = hv & (HSIZE - 1);
    uint32_t step = ((hv >> HASH_BITS) | 1u) & (HSIZE - 1);  // odd -> cycles whole table
    int slot = -1;
    for (int probe = 0; probe < MAX_PROBE; probe++) {
        int k = key[h];                       // cheap path: no atomic
        if (k == l) { slot = (int)h; break; }
        if (k == -1) {                        // maybe empty (or stale) -> resolve via CAS
            k = atomicCAS(&key[h], -1, l);
            if (k == -1 || k == l) { slot = (int)h; break; }
        }
        h = (h + step) & (HSIZE - 1);
    }
    slotidx[i] = slot;
    if (slot >= 0) atomicMin(&minidx[slot], i);
}

// K2: head flags (point i is head iff it is the min-index point of its voxel)
// reduced to per-block sums.
__global__ void k_blocksum_v2(const int* __restrict__ slotidx,
                              const int* __restrict__ minidx,
                              int* __restrict__ bsum, int NP) {
    __shared__ int s[BLK];
    int i = blockIdx.x * BLK + threadIdx.x;
    int f = 0;
    if (i < NP) {
        int sl = slotidx[i];
        if (sl >= 0) f = (minidx[sl] == i) ? 1 : 0;
    }
    s[threadIdx.x] = f;
    __syncthreads();
    for (int st = BLK / 2; st > 0; st >>= 1) {
        if (threadIdx.x < st) s[threadIdx.x] += s[threadIdx.x + st];
        __syncthreads();
    }
    if (threadIdx.x == 0) bsum[blockIdx.x] = s[0];
}

// K3: single-block (256-thread) exclusive scan of block sums; writes voxel_num.
__global__ void k_scan_v2(int* __restrict__ bsum, int nb, float* __restrict__ out_vnum) {
    __shared__ int s[BLK];
    __shared__ int carry;
    int tid = threadIdx.x;
    if (tid == 0) carry = 0;
    __syncthreads();
    for (int base = 0; base < nb; base += BLK) {
        int i = base + tid;
        int v = (i < nb) ? bsum[i] : 0;
        s[tid] = v;
        __syncthreads();
        for (int d = 1; d < BLK; d <<= 1) {
            int t = (tid >= d) ? s[tid - d] : 0;
            __syncthreads();
            s[tid] += t;
            __syncthreads();
        }
        int incl = s[tid];
        int c = carry;
        if (i < nb) bsum[i] = c + incl - v;   // exclusive offset
        __syncthreads();
        if (tid == BLK - 1) carry = c + incl; // chunk total
        __syncthreads();
    }
    if (tid == 0) {
        int t = carry;
        out_vnum[0] = (float)(t < MAX_VOXELS ? t : MAX_VOXELS);
    }
}

// K4: assign voxel ids to heads (rank = global exclusive prefix of head flags).
__global__ void k_rank_v2(const int* __restrict__ slotidx, const int* __restrict__ minidx,
                          const int* __restrict__ key, const int* __restrict__ bsum,
                          int* __restrict__ voxid, int* __restrict__ voxlin, int NP) {
    __shared__ int s[BLK];
    int i = blockIdx.x * BLK + threadIdx.x;
    int sl = (i < NP) ? slotidx[i] : -1;
    int f = (sl >= 0 && minidx[sl] == i) ? 1 : 0;
    s[threadIdx.x] = f;
    __syncthreads();
    for (int d = 1; d < BLK; d <<= 1) {
        int t = (threadIdx.x >= d) ? s[threadIdx.x - d] : 0;
        __syncthreads();
        s[threadIdx.x] += t;
        __syncthreads();
    }
    if (f) {
        int rank = bsum[blockIdx.x] + s[threadIdx.x] - 1;
        if (rank >= 0 && rank < MAX_VOXELS) {
            voxid[sl] = rank;
            voxlin[rank] = key[sl];
        }
    }
}

// K5: per-voxel counts + sorted 10-smallest point indices via atomicMin waterfall.
__global__ void k_slots_v2(const int* __restrict__ slotidx, const int* __restrict__ voxid,
                           int* __restrict__ cnt, int* __restrict__ slotarr, int NP) {
    int i = blockIdx.x * BLK + threadIdx.x;
    if (i >= NP) return;
    int sl = slotidx[i];
    if (sl < 0) return;
    int v = voxid[sl];
    if (v < 0 || v >= MAX_VOXELS) return;
    atomicAdd(&cnt[v], 1);
    int val = i;
    int base = v * MAX_POINTS;
    #pragma unroll
    for (int k = 0; k < MAX_POINTS; k++) {
        int old = atomicMin(&slotarr[base + k], val);
        if (old == EMPTY_SLOT) break;       // landed in empty slot, done
        val = (old > val) ? old : val;      // carry displaced (larger) value down
    }
}

// K6: write ALL outputs (d_out is poisoned before every timed replay).
__global__ void k_write_v2(const float* __restrict__ pts,
                           const float* __restrict__ vsz,
                           const float* __restrict__ crg,
                           const int* __restrict__ slotarr, const int* __restrict__ voxlin,
                           const int* __restrict__ cnt, float* __restrict__ out, int NP) {
    const int TOTV = MAX_VOXELS * MAX_POINTS;
    int t = blockIdx.x * BLK + threadIdx.x;
    if (t < TOTV) {
        int idx = slotarr[t];
        float o0 = 0.f, o1 = 0.f, o2 = 0.f, o3 = 0.f, o4 = 0.f;
        if (idx != EMPTY_SLOT && idx >= 0 && idx < NP) {
            const float* p = pts + idx * C;
            o0 = p[0]; o1 = p[1]; o2 = p[2]; o3 = p[3]; o4 = p[4];
        }
        float* dst = out + VOX_OFF + t * C;
        dst[0] = o0; dst[1] = o1; dst[2] = o2; dst[3] = o3; dst[4] = o4;
    } else if (t < TOTV + MAX_VOXELS) {
        int v = t - TOTV;
        int l = voxlin[v];
        float a = 0.f, b = 0.f, c2 = 0.f;
        if (l >= 0) {
            int gy = (int)rintf((crg[4] - crg[1]) / vsz[1]);
            int gz = (int)rintf((crg[5] - crg[2]) / vsz[2]);
            int cz = l % gz;
            int r  = l / gz;
            int cy = r % gy;
            int cx = r / gy;
            a = (float)cz; b = (float)cy; c2 = (float)cx;   // coors row = (z,y,x)
        }
        out[CO_OFF + v * 3 + 0] = a;
        out[CO_OFF + v * 3 + 1] = b;
        out[CO_OFF + v * 3 + 2] = c2;
        int cn = cnt[v];
        if (cn > MAX_POINTS) cn = MAX_POINTS;
        out[NPV_OFF + v] = (float)cn;
    }
}

extern "C" void kernel_launch(void* const* d_in, const int* in_sizes, int n_in,
                              void* d_out, int out_size, void* d_ws, size_t ws_size,
                              hipStream_t stream) {
    if (!d_out || !d_ws || n_in < 3) return;
    const float* pts = (const float*)d_in[0];
    const float* vsz = (const float*)d_in[1];
    const float* crg = (const float*)d_in[2];
    if (!pts || !vsz || !crg) return;
    const int NP = in_sizes[0] / C;
    if (NP <= 0) return;
    const int nb = (NP + BLK - 1) / BLK;

    // Workspace budget check (graceful bail -> visible absmax failure, not a crash)
    size_t need = ((size_t)NP + (size_t)nb + 3ull * HSIZE + 2ull * MAX_VOXELS
                   + (size_t)MAX_VOXELS * MAX_POINTS) * 4ull;
    if (ws_size < need) return;
    if ((size_t)out_size < (size_t)VN_OFF + 1) return;

    int* w = (int*)d_ws;
    int* slotidx = w; w += NP;
    int* bsum    = w; w += nb;
    int* key     = w; w += HSIZE;
    int* minidx  = w; w += HSIZE;
    int* voxid   = w; w += HSIZE;
    int* cnt     = w; w += MAX_VOXELS;
    int* voxlin  = w; w += MAX_VOXELS;
    int* slotarr = w; w += MAX_VOXELS * MAX_POINTS;

    float* out = (float*)d_out;

    const int init_n = MAX_VOXELS * MAX_POINTS;   // largest array; covers HSIZE too
    k_init_v2<<<(init_n + BLK - 1) / BLK, BLK, 0, stream>>>(key, minidx, voxid, cnt, voxlin, slotarr);
    k_quantize_v2<<<nb, BLK, 0, stream>>>(pts, vsz, crg, slotidx, key, minidx, NP);
    k_blocksum_v2<<<nb, BLK, 0, stream>>>(slotidx, minidx, bsum, NP);
    k_scan_v2<<<1, BLK, 0, stream>>>(bsum, nb, out + VN_OFF);
    k_rank_v2<<<nb, BLK, 0, stream>>>(slotidx, minidx, key, bsum, voxid, voxlin, NP);
    k_slots_v2<<<nb, BLK, 0, stream>>>(slotidx, voxid, cnt, slotarr, NP);

    const int tot = MAX_VOXELS * MAX_POINTS + MAX_VOXELS;
    k_write_v2<<<(tot + BLK - 1) / BLK, BLK, 0, stream>>>(pts, vsz, crg, slotarr, voxlin, cnt, out, NP);
}

// Round 6
// 541.436 us; speedup vs baseline: 195.7036x; 40.2739x over previous
//
#include <hip/hip_runtime.h>
#include <cstdint>

static constexpr int C     = 5;
static constexpr int MAXP  = 10;
static constexpr int MAXV  = 160000;
static constexpr int BLK   = 256;
static constexpr int RBITS = 6;
static constexpr int RBUCK = 1 << RBITS;   // 64 buckets
static constexpr int NPASS = 5;            // 30 bits >= 27-bit key space

// Output layout (float32, concatenated in reference return order)
static constexpr int VOX_OFF = 0;                           // 160000*10*5
static constexpr int CO_OFF  = MAXV * MAXP * C;             // 8,000,000
static constexpr int NPV_OFF = CO_OFF + MAXV * 3;           // 8,480,000
static constexpr int VN_OFF  = NPV_OFF + MAXV;              // 8,640,000

typedef unsigned long long u64;

// K1: quantize -> (key, idx) pairs; zero head-bitmask; publish TOTAL sentinel.
__global__ void kv6_lin(const float* __restrict__ pts, const float* __restrict__ vsz,
                        const float* __restrict__ crg,
                        int* __restrict__ key0, int* __restrict__ idx0,
                        u64* __restrict__ mask, int* __restrict__ ctrl, int NP, int NW) {
    int i = blockIdx.x * BLK + threadIdx.x;
    if (i < NW) mask[i] = 0ull;
    float vx = vsz[0], vy = vsz[1], vz = vsz[2];
    float x0 = crg[0], y0 = crg[1], z0 = crg[2];
    int gx = (int)rintf((crg[3] - x0) / vx);
    int gy = (int)rintf((crg[4] - y0) / vy);
    int gz = (int)rintf((crg[5] - z0) / vz);
    int total = gx * gy * gz;
    if (i == 0) ctrl[2] = total;
    if (i >= NP) return;
    float px = pts[i * C], py = pts[i * C + 1], pz = pts[i * C + 2];
    int cx = (int)floorf((px - x0) / vx);
    int cy = (int)floorf((py - y0) / vy);
    int cz = (int)floorf((pz - z0) / vz);
    bool valid = (cx >= 0) & (cx < gx) & (cy >= 0) & (cy < gy) & (cz >= 0) & (cz < gz);
    key0[i] = valid ? (cx * gy + cy) * gz + cz : total;   // sentinel sorts last
    idx0[i] = i;
}

// Sort pass A: per-block digit histogram (LDS atomics; counts are order-independent).
__global__ void kv6_hist(const int* __restrict__ key, int* __restrict__ hist,
                         int NP, int shift) {
    __shared__ int sh[RBUCK];
    int t = threadIdx.x, b = blockIdx.x, i = b * BLK + t;
    if (t < RBUCK) sh[t] = 0;
    __syncthreads();
    if (i < NP) atomicAdd(&sh[(key[i] >> shift) & (RBUCK - 1)], 1);
    __syncthreads();
    if (t < RBUCK) hist[b * RBUCK + t] = sh[t];
}

// Sort pass B: per-digit exclusive scan across blocks (grid = RBUCK, block d owns digit d).
__global__ void kv6_scanblocks(int* __restrict__ hist, int* __restrict__ dtot, int NB) {
    __shared__ int s[BLK];
    __shared__ int carry;
    int d = blockIdx.x, t = threadIdx.x;
    if (t == 0) carry = 0;
    __syncthreads();
    for (int base = 0; base < NB; base += BLK) {
        int b = base + t;
        int v = (b < NB) ? hist[b * RBUCK + d] : 0;
        s[t] = v; __syncthreads();
        for (int o = 1; o < BLK; o <<= 1) {
            int x = (t >= o) ? s[t - o] : 0; __syncthreads();
            s[t] += x; __syncthreads();
        }
        int incl = s[t], c = carry;
        if (b < NB) hist[b * RBUCK + d] = c + incl - v;
        __syncthreads();
        if (t == BLK - 1) carry = c + incl;
        __syncthreads();
    }
    if (t == 0) dtot[d] = carry;
}

// Sort pass C: exclusive scan of 64 digit totals.
__global__ void kv6_scandig(const int* __restrict__ dtot, int* __restrict__ dbase) {
    if (threadIdx.x == 0) {
        int a = 0;
        for (int d = 0; d < RBUCK; d++) { dbase[d] = a; a += dtot[d]; }
    }
}

// Sort pass D: stable scatter. Intra-block stable rank via wave ballot matching
// + cross-wave per-digit offsets in LDS.
__global__ void kv6_scatter(const int* __restrict__ skey, const int* __restrict__ sidx,
                            int* __restrict__ dkey, int* __restrict__ didx,
                            const int* __restrict__ hist, const int* __restrict__ dbase,
                            int NP, int shift) {
    __shared__ int whist[4][RBUCK];
    int t = threadIdx.x, b = blockIdx.x, i = b * BLK + t;
    int w = t >> 6, lane = t & 63;
    if (t < 4 * RBUCK) ((int*)whist)[t] = 0;
    __syncthreads();
    bool act = i < NP;
    int k = 0, d = 0;
    if (act) { k = skey[i]; d = (k >> shift) & (RBUCK - 1); }
    u64 am = __ballot(act);
    u64 m = am;
    #pragma unroll
    for (int bit = 0; bit < RBITS; bit++) {
        u64 bb = __ballot(act && ((d >> bit) & 1));
        m &= ((d >> bit) & 1) ? bb : ~bb;
    }
    m &= am;                                         // drop inactive lanes from group
    u64 below = m & ((lane == 0) ? 0ull : ((1ull << lane) - 1ull));
    int rw = __popcll(below);                        // stable rank within wave
    if (act && rw == 0) whist[w][d] = __popcll(m);   // group leader publishes count
    __syncthreads();
    if (act) {
        int off = 0;
        for (int w2 = 0; w2 < w; w2++) off += whist[w2][d];
        int dst = dbase[d] + hist[b * RBUCK + d] + off + rw;
        dkey[dst] = k;
        didx[dst] = sidx[i];
    }
}

// Heads (sorted order) + valid flags -> per-block sums.
__global__ void kv6_heads(const int* __restrict__ skey, int* __restrict__ bsumH,
                          int* __restrict__ bsumV, const int* __restrict__ ctrl, int NP) {
    __shared__ int sh[BLK], sv[BLK];
    int TOTAL = ctrl[2];
    int t = threadIdx.x, i = blockIdx.x * BLK + t;
    int h = 0, v = 0;
    if (i < NP) {
        int k = skey[i];
        if (k != TOTAL) { v = 1; h = (i == 0) || (skey[i - 1] != k); }
    }
    sh[t] = h; sv[t] = v;
    __syncthreads();
    for (int o = BLK / 2; o > 0; o >>= 1) {
        if (t < o) { sh[t] += sh[t + o]; sv[t] += sv[t + o]; }
        __syncthreads();
    }
    if (t == 0) { bsumH[blockIdx.x] = sh[0]; bsumV[blockIdx.x] = sv[0]; }
}

// Scan head block-sums in place (-> group-id offsets), G total, nvalid total, voxel_num.
__global__ void kv6_scanG(int* __restrict__ bsumH, const int* __restrict__ bsumV,
                          int NB, int* __restrict__ ctrl, float* __restrict__ out_vnum) {
    __shared__ int s[BLK];
    __shared__ int carry;
    int t = threadIdx.x;
    if (t == 0) carry = 0;
    __syncthreads();
    for (int base = 0; base < NB; base += BLK) {
        int b = base + t;
        int v = (b < NB) ? bsumH[b] : 0;
        s[t] = v; __syncthreads();
        for (int o = 1; o < BLK; o <<= 1) {
            int x = (t >= o) ? s[t - o] : 0; __syncthreads();
            s[t] += x; __syncthreads();
        }
        int incl = s[t], c = carry;
        if (b < NB) bsumH[b] = c + incl - v;
        __syncthreads();
        if (t == BLK - 1) carry = c + incl;
        __syncthreads();
    }
    if (t == 0) { ctrl[0] = carry; out_vnum[0] = (float)(carry < MAXV ? carry : MAXV); }
    __syncthreads();
    int acc = 0;
    for (int base = 0; base < NB; base += BLK) { int b = base + t; if (b < NB) acc += bsumV[b]; }
    s[t] = acc;
    __syncthreads();
    for (int o = BLK / 2; o > 0; o >>= 1) { if (t < o) s[t] += s[t + o]; __syncthreads(); }
    if (t == 0) ctrl[1] = s[0];
}

// Emit per-group records: gstart, head's original index; set head bit in bitmask.
__global__ void kv6_heads2(const int* __restrict__ skey, const int* __restrict__ sidx,
                           const int* __restrict__ bsumH, int* __restrict__ gstart,
                           int* __restrict__ ghead, u64* __restrict__ mask,
                           const int* __restrict__ ctrl, int NP) {
    __shared__ int s[BLK];
    int TOTAL = ctrl[2];
    int t = threadIdx.x, i = blockIdx.x * BLK + t;
    int h = 0;
    if (i < NP) {
        int k = skey[i];
        if (k != TOTAL) h = (i == 0) || (skey[i - 1] != k);
    }
    s[t] = h;
    __syncthreads();
    for (int o = 1; o < BLK; o <<= 1) {
        int x = (t >= o) ? s[t - o] : 0; __syncthreads();
        s[t] += x; __syncthreads();
    }
    if (h) {
        int g = bsumH[blockIdx.x] + s[t] - 1;
        gstart[g] = i;
        int io = sidx[i];
        ghead[g] = io;
        atomicOr(&mask[io >> 6], 1ull << (io & 63));
    }
}

// Exclusive prefix of per-word popcounts of the head bitmask.
__global__ void kv6_wpfx(const u64* __restrict__ mask, int* __restrict__ wpfx, int NW) {
    __shared__ int s[BLK];
    __shared__ int carry;
    int t = threadIdx.x;
    if (t == 0) carry = 0;
    __syncthreads();
    for (int base = 0; base < NW; base += BLK) {
        int b = base + t;
        int v = (b < NW) ? __popcll(mask[b]) : 0;
        s[t] = v; __syncthreads();
        for (int o = 1; o < BLK; o <<= 1) {
            int x = (t >= o) ? s[t - o] : 0; __syncthreads();
            s[t] += x; __syncthreads();
        }
        int incl = s[t], c = carry;
        if (b < NW) wpfx[b] = c + incl - v;
        __syncthreads();
        if (t == BLK - 1) carry = c + incl;
        __syncthreads();
    }
}

// Zero-fill voxels + coors + npv (out is poisoned before every timed replay).
__global__ void kv6_zero(float* __restrict__ out) {
    int i = blockIdx.x * BLK + threadIdx.x;
    if (i < VN_OFF) out[i] = 0.f;
}

__device__ __forceinline__ int vox_rank(const u64* mask, const int* wpfx, int io) {
    return wpfx[io >> 6] + __popcll(mask[io >> 6] & ((1ull << (io & 63)) - 1ull));
}

// Per-voxel outputs: coors (z,y,x) + clamped counts.
__global__ void kv6_pervox(const int* __restrict__ gstart, const int* __restrict__ ghead,
                           const int* __restrict__ skey, const u64* __restrict__ mask,
                           const int* __restrict__ wpfx, const int* __restrict__ ctrl,
                           const float* __restrict__ vsz, const float* __restrict__ crg,
                           float* __restrict__ out) {
    int g = blockIdx.x * BLK + threadIdx.x;
    int G = ctrl[0], nval = ctrl[1];
    if (g >= G) return;
    int io = ghead[g];
    int vid = vox_rank(mask, wpfx, io);
    if (vid >= MAXV) return;
    int p0 = gstart[g];
    int k = skey[p0];
    int gy = (int)rintf((crg[4] - crg[1]) / vsz[1]);
    int gz = (int)rintf((crg[5] - crg[2]) / vsz[2]);
    int cz = k % gz; int r = k / gz; int cy = r % gy; int cx = r / gy;
    out[CO_OFF + vid * 3 + 0] = (float)cz;
    out[CO_OFF + vid * 3 + 1] = (float)cy;
    out[CO_OFF + vid * 3 + 2] = (float)cx;
    int gsz = ((g + 1 < G) ? gstart[g + 1] : nval) - p0;
    out[NPV_OFF + vid] = (float)(gsz < MAXP ? gsz : MAXP);
}

// Emit voxel point payloads.
__global__ void kv6_emit(const int* __restrict__ skey, const int* __restrict__ sidx,
                         const int* __restrict__ gstart, const int* __restrict__ ghead,
                         const u64* __restrict__ mask, const int* __restrict__ wpfx,
                         const int* __restrict__ ctrl, const float* __restrict__ pts,
                         float* __restrict__ out, int NP) {
    int p = blockIdx.x * BLK + threadIdx.x;
    if (p >= NP) return;
    int TOTAL = ctrl[2], G = ctrl[0];
    int k = skey[p];
    if (k == TOTAL) return;                 // invalids sorted to the end
    int lo = 0, hi = G - 1;                 // G >= 1 here (a valid element exists)
    while (lo < hi) {                       // largest g with gstart[g] <= p
        int mid = (lo + hi + 1) >> 1;
        if (gstart[mid] <= p) lo = mid; else hi = mid - 1;
    }
    int g = lo;
    int slot = p - gstart[g];
    if (slot >= MAXP) return;
    int vid = vox_rank(mask, wpfx, ghead[g]);
    if (vid >= MAXV) return;
    int iorig = sidx[p];
    const float* src = pts + iorig * C;
    float* dst = out + (vid * MAXP + slot) * C;
    dst[0] = src[0]; dst[1] = src[1]; dst[2] = src[2]; dst[3] = src[3]; dst[4] = src[4];
}

extern "C" void kernel_launch(void* const* d_in, const int* in_sizes, int n_in,
                              void* d_out, int out_size, void* d_ws, size_t ws_size,
                              hipStream_t stream) {
    if (!d_out || !d_ws || n_in < 3) return;
    const float* pts = (const float*)d_in[0];
    const float* vsz = (const float*)d_in[1];
    const float* crg = (const float*)d_in[2];
    if (!pts || !vsz || !crg) return;
    const int NP = in_sizes[0] / C;
    if (NP <= 0) return;
    const int NB = (NP + BLK - 1) / BLK;
    const int NW = (NP + 63) / 64;

    // Workspace budget (ints): 4N pairs + hist + 2 block-sum arrays + dtot/dbase
    // + wpfx + ctrl + pad + mask(2 ints per word)
    size_t need_ints = 4ull * NP + (size_t)RBUCK * NB + 2ull * NB + 2 * RBUCK
                     + (size_t)NW + 8 + 2 + 2ull * NW;
    if (ws_size < need_ints * 4ull) return;
    if ((size_t)out_size < (size_t)VN_OFF + 1) return;

    int* w = (int*)d_ws;
    int* key0  = w; w += NP;
    int* idx0  = w; w += NP;
    int* key1  = w; w += NP;
    int* idx1  = w; w += NP;
    int* hist  = w; w += (size_t)RBUCK * NB;
    int* bsumH = w; w += NB;
    int* bsumV = w; w += NB;
    int* dtot  = w; w += RBUCK;
    int* dbase = w; w += RBUCK;
    int* wpfx  = w; w += NW;
    int* ctrl  = w; w += 8;
    w += ((uintptr_t)w & 7) ? 1 : 0;        // 8-byte align for u64 mask
    u64* mask  = (u64*)w;                   // NW words

    float* out = (float*)d_out;

    kv6_lin<<<NB, BLK, 0, stream>>>(pts, vsz, crg, key0, idx0, mask, ctrl, NP, NW);
    kv6_zero<<<(VN_OFF + BLK - 1) / BLK, BLK, 0, stream>>>(out);

    // 5-pass stable LSD radix sort: key0/idx0 -> ... -> key1/idx1 (odd passes)
    int* ka = key0; int* ia = idx0; int* kb = key1; int* ib = idx1;
    for (int pass = 0; pass < NPASS; pass++) {
        int shift = pass * RBITS;
        kv6_hist<<<NB, BLK, 0, stream>>>(ka, hist, NP, shift);
        kv6_scanblocks<<<RBUCK, BLK, 0, stream>>>(hist, dtot, NB);
        kv6_scandig<<<1, 64, 0, stream>>>(dtot, dbase);
        kv6_scatter<<<NB, BLK, 0, stream>>>(ka, ia, kb, ib, hist, dbase, NP, shift);
        int* tk = ka; ka = kb; kb = tk;
        int* ti = ia; ia = ib; ib = ti;
    }
    // sorted arrays: ka = key1, ia = idx1 (NPASS odd). kb/ib (= key0/idx0) now free.
    int* skey = ka; int* sidx = ia;
    int* gstart = kb; int* ghead = ib;      // reuse freed ping-pong buffers

    kv6_heads<<<NB, BLK, 0, stream>>>(skey, bsumH, bsumV, ctrl, NP);
    kv6_scanG<<<1, BLK, 0, stream>>>(bsumH, bsumV, NB, ctrl, out + VN_OFF);
    kv6_heads2<<<NB, BLK, 0, stream>>>(skey, sidx, bsumH, gstart, ghead, mask, ctrl, NP);
    kv6_wpfx<<<1, BLK, 0, stream>>>(mask, wpfx, NW);
    kv6_pervox<<<NB, BLK, 0, stream>>>(gstart, ghead, skey, mask, wpfx, ctrl, vsz, crg, out);
    kv6_emit<<<NB, BLK, 0, stream>>>(skey, sidx, gstart, ghead, mask, wpfx, ctrl, pts, out, NP);
}

// Round 7
// 310.566 us; speedup vs baseline: 341.1870x; 1.7434x over previous
//
#include <hip/hip_runtime.h>
#include <cstdint>

static constexpr int C     = 5;
static constexpr int MAXP  = 10;
static constexpr int MAXV  = 160000;
static constexpr int BLK   = 256;
static constexpr int RBITS = 9;
static constexpr int RBUCK = 1 << RBITS;   // 512 buckets
static constexpr int EPT   = 8;            // elements per thread in sort/heads kernels
static constexpr int ELEMS = BLK * EPT;    // 2048 elements per block
static constexpr int NPASS = 3;            // 27 bits >= 26.3-bit key space

// Output layout (float32, concatenated in reference return order)
static constexpr int VOX_OFF = 0;                           // 160000*10*5
static constexpr int CO_OFF  = MAXV * MAXP * C;             // 8,000,000
static constexpr int NPV_OFF = CO_OFF + MAXV * 3;           // 8,480,000
static constexpr int VN_OFF  = NPV_OFF + MAXV;              // 8,640,000

typedef unsigned long long u64;

// K1: quantize -> int keys; zero head-bitmask; publish TOTAL sentinel.
__global__ void kv7_lin(const float* __restrict__ pts, const float* __restrict__ vsz,
                        const float* __restrict__ crg, int* __restrict__ key0,
                        u64* __restrict__ mask, int* __restrict__ ctrl, int NP, int NW) {
    int i = blockIdx.x * BLK + threadIdx.x;
    if (i < NW) mask[i] = 0ull;
    float vx = vsz[0], vy = vsz[1], vz = vsz[2];
    float x0 = crg[0], y0 = crg[1], z0 = crg[2];
    int gx = (int)rintf((crg[3] - x0) / vx);
    int gy = (int)rintf((crg[4] - y0) / vy);
    int gz = (int)rintf((crg[5] - z0) / vz);
    int total = gx * gy * gz;
    if (i == 0) ctrl[2] = total;
    if (i >= NP) return;
    float px = pts[i * C], py = pts[i * C + 1], pz = pts[i * C + 2];
    int cx = (int)floorf((px - x0) / vx);
    int cy = (int)floorf((py - y0) / vy);
    int cz = (int)floorf((pz - z0) / vz);
    bool valid = (cx >= 0) & (cx < gx) & (cy >= 0) & (cy < gy) & (cz >= 0) & (cz < gz);
    key0[i] = valid ? (cx * gy + cy) * gz + cz : total;   // sentinel sorts last
}

// Histogram, pass 0 (int keys).
__global__ void kv7_hist_i(const int* __restrict__ key, int* __restrict__ hist, int NP) {
    __shared__ int sh[RBUCK];
    int t = threadIdx.x, b = blockIdx.x;
    for (int d = t; d < RBUCK; d += BLK) sh[d] = 0;
    __syncthreads();
    int base = b * ELEMS;
    #pragma unroll
    for (int r = 0; r < EPT; r++) {
        int i = base + r * BLK + t;
        if (i < NP) atomicAdd(&sh[key[i] & (RBUCK - 1)], 1);
    }
    __syncthreads();
    for (int d = t; d < RBUCK; d += BLK) hist[b * RBUCK + d] = sh[d];
}

// Histogram, passes 1..2 (u64 pairs, digit from high 32 bits).
__global__ void kv7_hist_p(const u64* __restrict__ pair, int* __restrict__ hist,
                           int NP, int shift) {
    __shared__ int sh[RBUCK];
    int t = threadIdx.x, b = blockIdx.x;
    for (int d = t; d < RBUCK; d += BLK) sh[d] = 0;
    __syncthreads();
    int base = b * ELEMS;
    #pragma unroll
    for (int r = 0; r < EPT; r++) {
        int i = base + r * BLK + t;
        if (i < NP) atomicAdd(&sh[(int)((pair[i] >> (32 + shift)) & (RBUCK - 1))], 1);
    }
    __syncthreads();
    for (int d = t; d < RBUCK; d += BLK) hist[b * RBUCK + d] = sh[d];
}

// Per-digit exclusive scan across blocks (grid = RBUCK; block d owns digit d).
__global__ void kv7_scanb(int* __restrict__ hist, int* __restrict__ dtot, int NB) {
    __shared__ int s[BLK];
    __shared__ int carry;
    int d = blockIdx.x, t = threadIdx.x;
    if (t == 0) carry = 0;
    __syncthreads();
    for (int base = 0; base < NB; base += BLK) {
        int b = base + t;
        int v = (b < NB) ? hist[b * RBUCK + d] : 0;
        s[t] = v; __syncthreads();
        for (int o = 1; o < BLK; o <<= 1) {
            int x = (t >= o) ? s[t - o] : 0; __syncthreads();
            s[t] += x; __syncthreads();
        }
        int incl = s[t], c = carry;
        if (b < NB) hist[b * RBUCK + d] = c + incl - v;
        __syncthreads();
        if (t == BLK - 1) carry = c + incl;
        __syncthreads();
    }
    if (t == 0) dtot[d] = carry;
}

// Exclusive scan of 512 digit totals (one 512-thread block, LDS Hillis-Steele).
__global__ void kv7_scand(const int* __restrict__ dtot, int* __restrict__ dbase) {
    __shared__ int s[RBUCK];
    int t = threadIdx.x;
    int v = dtot[t];
    s[t] = v;
    __syncthreads();
    for (int o = 1; o < RBUCK; o <<= 1) {
        int x = (t >= o) ? s[t - o] : 0; __syncthreads();
        s[t] += x; __syncthreads();
    }
    dbase[t] = s[t] - v;
}

// Stable scatter body: sub-batch-major order, ballot match intra-wave,
// whist cross-wave, cnt running across sub-batches. cnt pre-folds global base.
#define SCATTER_BODY(GET_KEY, GET_IDX)                                          \
    __shared__ int cnt[RBUCK];                                                  \
    __shared__ int whist[4][RBUCK];                                             \
    int t = threadIdx.x, b = blockIdx.x;                                        \
    int w = t >> 6, lane = t & 63;                                              \
    for (int d = t; d < RBUCK; d += BLK) cnt[d] = dbase[d] + hist[b * RBUCK + d]; \
    int base = b * ELEMS;                                                       \
    for (int r = 0; r < EPT; r++) {                                             \
        int i = base + r * BLK + t;                                             \
        bool act = i < NP;                                                      \
        int k = 0, idx = 0, d = 0;                                              \
        if (act) { GET_KEY; GET_IDX; d = (k >> shift) & (RBUCK - 1); }          \
        for (int x = t; x < 4 * RBUCK; x += BLK) ((int*)whist)[x] = 0;          \
        __syncthreads();                                                        \
        u64 m = __ballot(act);                                                  \
        _Pragma("unroll")                                                       \
        for (int bit = 0; bit < RBITS; bit++) {                                 \
            u64 bb = __ballot(act && ((d >> bit) & 1));                         \
            m &= ((d >> bit) & 1) ? bb : ~bb;                                   \
        }                                                                       \
        int rw = __popcll(m & ((1ull << lane) - 1ull));                         \
        if (act && rw == 0) whist[w][d] = __popcll(m);                          \
        __syncthreads();                                                        \
        if (act) {                                                              \
            int off = cnt[d];                                                   \
            for (int w2 = 0; w2 < w; w2++) off += whist[w2][d];                 \
            dpair[off + rw] = ((u64)(uint32_t)k << 32) | (uint32_t)idx;         \
        }                                                                       \
        __syncthreads();                                                        \
        for (int d2 = t; d2 < RBUCK; d2 += BLK) {                               \
            int ssum = 0;                                                       \
            _Pragma("unroll")                                                   \
            for (int w2 = 0; w2 < 4; w2++) ssum += whist[w2][d2];               \
            cnt[d2] += ssum;                                                    \
        }                                                                       \
        __syncthreads();                                                        \
    }

// Scatter pass 0: int keys in, pairs out (idx = i, shift = 0).
__global__ void kv7_scat0(const int* __restrict__ skey, u64* __restrict__ dpair,
                          const int* __restrict__ hist, const int* __restrict__ dbase,
                          int NP) {
    const int shift = 0;
    SCATTER_BODY(k = skey[i], idx = i)
}

// Scatter passes 1..2: pairs in, pairs out.
__global__ void kv7_scatp(const u64* __restrict__ spair, u64* __restrict__ dpair,
                          const int* __restrict__ hist, const int* __restrict__ dbase,
                          int NP, int shift) {
    u64 pv;
    SCATTER_BODY(pv = spair[i]; k = (int)(pv >> 32), idx = (int)(pv & 0xFFFFFFFFull))
}

// Heads + valid flags -> per-block sums (EPT elements per thread).
__global__ void kv7_heads(const u64* __restrict__ pair, int* __restrict__ bsumH,
                          int* __restrict__ bsumV, const int* __restrict__ ctrl, int NP) {
    __shared__ int sh[BLK], sv[BLK];
    int TOTAL = ctrl[2];
    int t = threadIdx.x, b = blockIdx.x;
    int base = b * ELEMS;
    int hs = 0, vs = 0;
    #pragma unroll
    for (int r = 0; r < EPT; r++) {
        int i = base + r * BLK + t;
        if (i < NP) {
            int k = (int)(pair[i] >> 32);
            if (k != TOTAL) {
                vs++;
                hs += (i == 0) || ((int)(pair[i - 1] >> 32) != k);
            }
        }
    }
    sh[t] = hs; sv[t] = vs;
    __syncthreads();
    for (int o = BLK / 2; o > 0; o >>= 1) {
        if (t < o) { sh[t] += sh[t + o]; sv[t] += sv[t + o]; }
        __syncthreads();
    }
    if (t == 0) { bsumH[b] = sh[0]; bsumV[b] = sv[0]; }
}

// Scan head block-sums in place; G -> ctrl[0], nvalid -> ctrl[1], voxel_num -> out.
__global__ void kv7_scanG(int* __restrict__ bsumH, const int* __restrict__ bsumV,
                          int NB, int* __restrict__ ctrl, float* __restrict__ out_vnum) {
    __shared__ int s[BLK];
    __shared__ int carry;
    int t = threadIdx.x;
    if (t == 0) carry = 0;
    __syncthreads();
    for (int base = 0; base < NB; base += BLK) {
        int b = base + t;
        int v = (b < NB) ? bsumH[b] : 0;
        s[t] = v; __syncthreads();
        for (int o = 1; o < BLK; o <<= 1) {
            int x = (t >= o) ? s[t - o] : 0; __syncthreads();
            s[t] += x; __syncthreads();
        }
        int incl = s[t], c = carry;
        if (b < NB) bsumH[b] = c + incl - v;
        __syncthreads();
        if (t == BLK - 1) carry = c + incl;
        __syncthreads();
    }
    if (t == 0) { ctrl[0] = carry; out_vnum[0] = (float)(carry < MAXV ? carry : MAXV); }
    __syncthreads();
    int acc = 0;
    for (int base = 0; base < NB; base += BLK) { int b = base + t; if (b < NB) acc += bsumV[b]; }
    s[t] = acc;
    __syncthreads();
    for (int o = BLK / 2; o > 0; o >>= 1) { if (t < o) s[t] += s[t + o]; __syncthreads(); }
    if (t == 0) ctrl[1] = s[0];
}

// Emit per-group records (stable in-block flag prefix, EPT sub-batches).
__global__ void kv7_heads2(const u64* __restrict__ pair, const int* __restrict__ bsumH,
                           int* __restrict__ gstart, int* __restrict__ ghead,
                           u64* __restrict__ mask, const int* __restrict__ ctrl, int NP) {
    __shared__ int wcnt[4];
    __shared__ int run;
    int TOTAL = ctrl[2];
    int t = threadIdx.x, b = blockIdx.x;
    int w = t >> 6, lane = t & 63;
    if (t == 0) run = 0;
    __syncthreads();
    int base = b * ELEMS;
    for (int r = 0; r < EPT; r++) {
        int i = base + r * BLK + t;
        int h = 0; u64 pv = 0;
        if (i < NP) {
            pv = pair[i];
            int k = (int)(pv >> 32);
            if (k != TOTAL) h = (i == 0) || ((int)(pair[i - 1] >> 32) != k);
        }
        u64 bm = __ballot(h);
        int rw = __popcll(bm & ((1ull << lane) - 1ull));
        if (lane == 0) wcnt[w] = __popcll(bm);
        __syncthreads();
        if (h) {
            int off = run;
            for (int w2 = 0; w2 < w; w2++) off += wcnt[w2];
            int g = bsumH[b] + off + rw;
            gstart[g] = i;
            int io = (int)(pv & 0xFFFFFFFFull);
            ghead[g] = io;
            atomicOr(&mask[io >> 6], 1ull << (io & 63));
        }
        __syncthreads();
        if (t == 0) run += wcnt[0] + wcnt[1] + wcnt[2] + wcnt[3];
        __syncthreads();
    }
}

// wpfx 3-phase parallel scan over NW popcounts.
__global__ void kv7_wpA(const u64* __restrict__ mask, int* __restrict__ wsum, int NW) {
    __shared__ int s[BLK];
    int t = threadIdx.x, i = blockIdx.x * BLK + t;
    s[t] = (i < NW) ? __popcll(mask[i]) : 0;
    __syncthreads();
    for (int o = BLK / 2; o > 0; o >>= 1) { if (t < o) s[t] += s[t + o]; __syncthreads(); }
    if (t == 0) wsum[blockIdx.x] = s[0];
}
__global__ void kv7_wpB(int* __restrict__ wsum, int nws) {
    __shared__ int s[128];
    int t = threadIdx.x;
    int v = (t < nws) ? wsum[t] : 0;
    s[t] = v;
    __syncthreads();
    for (int o = 1; o < 128; o <<= 1) {
        int x = (t >= o) ? s[t - o] : 0; __syncthreads();
        s[t] += x; __syncthreads();
    }
    if (t < nws) wsum[t] = s[t] - v;   // exclusive
}
__global__ void kv7_wpC(const u64* __restrict__ mask, const int* __restrict__ wsum,
                        int* __restrict__ wpfx, int NW) {
    __shared__ int s[BLK];
    int t = threadIdx.x, i = blockIdx.x * BLK + t;
    int v = (i < NW) ? __popcll(mask[i]) : 0;
    s[t] = v;
    __syncthreads();
    for (int o = 1; o < BLK; o <<= 1) {
        int x = (t >= o) ? s[t - o] : 0; __syncthreads();
        s[t] += x; __syncthreads();
    }
    if (i < NW) wpfx[i] = wsum[blockIdx.x] + s[t] - v;
}

// Zero-fill voxels + coors + npv (out is poisoned before every timed replay).
__global__ void kv7_zero(float* __restrict__ out) {
    int i = blockIdx.x * BLK + threadIdx.x;
    if (i < VN_OFF) out[i] = 0.f;
}

__device__ __forceinline__ int vox_rank(const u64* mask, const int* wpfx, int io) {
    return wpfx[io >> 6] + __popcll(mask[io >> 6] & ((1ull << (io & 63)) - 1ull));
}

// Per-voxel outputs: coors (z,y,x) + clamped counts.
__global__ void kv7_pervox(const int* __restrict__ gstart, const int* __restrict__ ghead,
                           const u64* __restrict__ pair, const u64* __restrict__ mask,
                           const int* __restrict__ wpfx, const int* __restrict__ ctrl,
                           const float* __restrict__ vsz, const float* __restrict__ crg,
                           float* __restrict__ out) {
    int g = blockIdx.x * BLK + threadIdx.x;
    int G = ctrl[0], nval = ctrl[1];
    if (g >= G) return;
    int io = ghead[g];
    int vid = vox_rank(mask, wpfx, io);
    if (vid >= MAXV) return;
    int p0 = gstart[g];
    int k = (int)(pair[p0] >> 32);
    int gy = (int)rintf((crg[4] - crg[1]) / vsz[1]);
    int gz = (int)rintf((crg[5] - crg[2]) / vsz[2]);
    int cz = k % gz; int rr = k / gz; int cy = rr % gy; int cx = rr / gy;
    out[CO_OFF + vid * 3 + 0] = (float)cz;
    out[CO_OFF + vid * 3 + 1] = (float)cy;
    out[CO_OFF + vid * 3 + 2] = (float)cx;
    int gsz = ((g + 1 < G) ? gstart[g + 1] : nval) - p0;
    out[NPV_OFF + vid] = (float)(gsz < MAXP ? gsz : MAXP);
}

// Emit voxel point payloads.
__global__ void kv7_emit(const u64* __restrict__ pair, const int* __restrict__ gstart,
                         const int* __restrict__ ghead, const u64* __restrict__ mask,
                         const int* __restrict__ wpfx, const int* __restrict__ ctrl,
                         const float* __restrict__ pts, float* __restrict__ out, int NP) {
    int p = blockIdx.x * BLK + threadIdx.x;
    if (p >= NP) return;
    int TOTAL = ctrl[2], G = ctrl[0];
    u64 pv = pair[p];
    int k = (int)(pv >> 32);
    if (k == TOTAL) return;                 // invalids sorted to the end
    int lo = 0, hi = G - 1;                 // G >= 1 here (a valid element exists)
    while (lo < hi) {                       // largest g with gstart[g] <= p
        int mid = (lo + hi + 1) >> 1;
        if (gstart[mid] <= p) lo = mid; else hi = mid - 1;
    }
    int g = lo;
    int slot = p - gstart[g];
    if (slot >= MAXP) return;
    int vid = vox_rank(mask, wpfx, ghead[g]);
    if (vid >= MAXV) return;
    int iorig = (int)(pv & 0xFFFFFFFFull);
    const float* src = pts + iorig * C;
    float* dst = out + (vid * MAXP + slot) * C;
    dst[0] = src[0]; dst[1] = src[1]; dst[2] = src[2]; dst[3] = src[3]; dst[4] = src[4];
}

extern "C" void kernel_launch(void* const* d_in, const int* in_sizes, int n_in,
                              void* d_out, int out_size, void* d_ws, size_t ws_size,
                              hipStream_t stream) {
    if (!d_out || !d_ws || n_in < 3) return;
    const float* pts = (const float*)d_in[0];
    const float* vsz = (const float*)d_in[1];
    const float* crg = (const float*)d_in[2];
    if (!pts || !vsz || !crg) return;
    const int NP  = in_sizes[0] / C;
    if (NP <= 0) return;
    const int NB  = (NP + ELEMS - 1) / ELEMS;     // sort/heads blocks (586)
    const int NBS = (NP + BLK - 1) / BLK;         // 1-elem kernels   (4688)
    const int NW  = (NP + 63) / 64;               // bitmask words    (18750)
    const int NWS = (NW + BLK - 1) / BLK;         // wpfx blocks      (74)
    if (NWS > 128) return;

    // Workspace budget in bytes (proven-safe <= 20.66 MB footprint)
    size_t need = 2ull * NP * 8ull                       // pairA + pairB (key0 aliases pairB)
                + (size_t)RBUCK * NB * 4ull              // hist
                + 2ull * NB * 4ull                       // bsumH, bsumV
                + 2ull * RBUCK * 4ull                    // dtot, dbase
                + (size_t)NW * 4ull                      // wpfx
                + 128ull * 4ull + 8ull * 4ull + 16ull    // wsum, ctrl, align pad
                + (size_t)NW * 8ull;                     // mask
    if (ws_size < need) return;
    if ((size_t)out_size < (size_t)VN_OFF + 1) return;

    u64* pairA = (u64*)d_ws;
    u64* pairB = pairA + NP;
    int* key0  = (int*)pairB;                     // aliases pairB (dead before pass 1 writes)
    int* w     = (int*)(pairB + NP);
    int* hist  = w; w += (size_t)RBUCK * NB;
    int* bsumH = w; w += NB;
    int* bsumV = w; w += NB;
    int* dtot  = w; w += RBUCK;
    int* dbase = w; w += RBUCK;
    int* wpfx  = w; w += NW;
    int* wsum  = w; w += 128;
    int* ctrl  = w; w += 8;
    w += ((uintptr_t)w & 7) ? 1 : 0;              // 8-byte align
    u64* mask  = (u64*)w;                         // NW words

    float* out = (float*)d_out;

    kv7_lin<<<NBS, BLK, 0, stream>>>(pts, vsz, crg, key0, mask, ctrl, NP, NW);
    kv7_zero<<<(VN_OFF + BLK - 1) / BLK, BLK, 0, stream>>>(out);

    // Pass 0: key0 (int) -> pairA
    kv7_hist_i<<<NB, BLK, 0, stream>>>(key0, hist, NP);
    kv7_scanb<<<RBUCK, BLK, 0, stream>>>(hist, dtot, NB);
    kv7_scand<<<1, RBUCK, 0, stream>>>(dtot, dbase);
    kv7_scat0<<<NB, BLK, 0, stream>>>(key0, pairA, hist, dbase, NP);
    // Pass 1: pairA -> pairB (clobbers key0 — dead)
    kv7_hist_p<<<NB, BLK, 0, stream>>>(pairA, hist, NP, RBITS);
    kv7_scanb<<<RBUCK, BLK, 0, stream>>>(hist, dtot, NB);
    kv7_scand<<<1, RBUCK, 0, stream>>>(dtot, dbase);
    kv7_scatp<<<NB, BLK, 0, stream>>>(pairA, pairB, hist, dbase, NP, RBITS);
    // Pass 2: pairB -> pairA (final sorted order)
    kv7_hist_p<<<NB, BLK, 0, stream>>>(pairB, hist, NP, 2 * RBITS);
    kv7_scanb<<<RBUCK, BLK, 0, stream>>>(hist, dtot, NB);
    kv7_scand<<<1, RBUCK, 0, stream>>>(dtot, dbase);
    kv7_scatp<<<NB, BLK, 0, stream>>>(pairB, pairA, hist, dbase, NP, 2 * RBITS);

    int* gstart = (int*)pairB;                    // pairB free after pass 2
    int* ghead  = gstart + NP;

    kv7_heads<<<NB, BLK, 0, stream>>>(pairA, bsumH, bsumV, ctrl, NP);
    kv7_scanG<<<1, BLK, 0, stream>>>(bsumH, bsumV, NB, ctrl, out + VN_OFF);
    kv7_heads2<<<NB, BLK, 0, stream>>>(pairA, bsumH, gstart, ghead, mask, ctrl, NP);
    kv7_wpA<<<NWS, BLK, 0, stream>>>(mask, wsum, NW);
    kv7_wpB<<<1, 128, 0, stream>>>(wsum, NWS);
    kv7_wpC<<<NWS, BLK, 0, stream>>>(mask, wsum, wpfx, NW);
    kv7_pervox<<<NBS, BLK, 0, stream>>>(gstart, ghead, pairA, mask, wpfx, ctrl, vsz, crg, out);
    kv7_emit<<<NBS, BLK, 0, stream>>>(pairA, gstart, ghead, mask, wpfx, ctrl, pts, out, NP);
}

// Round 8
// 280.934 us; speedup vs baseline: 377.1738x; 1.1055x over previous
//
#include <hip/hip_runtime.h>
#include <cstdint>

static constexpr int C     = 5;
static constexpr int MAXP  = 10;
static constexpr int MAXV  = 160000;
static constexpr int BLK   = 256;
static constexpr int RBITS = 9;
static constexpr int RBUCK = 1 << RBITS;   // 512 buckets
static constexpr int EPT   = 8;            // elements per thread in sort/heads kernels
static constexpr int ELEMS = BLK * EPT;    // 2048 elements per block

// Output layout (float32, concatenated in reference return order)
static constexpr int VOX_OFF = 0;                           // 160000*10*5
static constexpr int CO_OFF  = MAXV * MAXP * C;             // 8,000,000
static constexpr int NPV_OFF = CO_OFF + MAXV * 3;           // 8,480,000
static constexpr int VN_OFF  = NPV_OFF + MAXV;              // 8,640,000

typedef unsigned long long u64;
static constexpr u64 BYTEMUL = 0x0101010101010101ull;

// K1: quantize -> int keys; publish TOTAL sentinel.
__global__ void kv8_lin(const float* __restrict__ pts, const float* __restrict__ vsz,
                        const float* __restrict__ crg, int* __restrict__ key0,
                        int* __restrict__ ctrl, int NP) {
    int i = blockIdx.x * BLK + threadIdx.x;
    float vx = vsz[0], vy = vsz[1], vz = vsz[2];
    float x0 = crg[0], y0 = crg[1], z0 = crg[2];
    int gx = (int)rintf((crg[3] - x0) / vx);
    int gy = (int)rintf((crg[4] - y0) / vy);
    int gz = (int)rintf((crg[5] - z0) / vz);
    int total = gx * gy * gz;
    if (i == 0) ctrl[2] = total;
    if (i >= NP) return;
    float px = pts[i * C], py = pts[i * C + 1], pz = pts[i * C + 2];
    int cx = (int)floorf((px - x0) / vx);
    int cy = (int)floorf((py - y0) / vy);
    int cz = (int)floorf((pz - z0) / vz);
    bool valid = (cx >= 0) & (cx < gx) & (cy >= 0) & (cy < gy) & (cz >= 0) & (cz < gz);
    key0[i] = valid ? (cx * gy + cy) * gz + cz : total;   // sentinel sorts last
}

// Histogram, pass 0 (int keys).
__global__ void kv8_hist_i(const int* __restrict__ key, int* __restrict__ hist, int NP) {
    __shared__ int sh[RBUCK];
    int t = threadIdx.x, b = blockIdx.x;
    for (int d = t; d < RBUCK; d += BLK) sh[d] = 0;
    __syncthreads();
    int base = b * ELEMS;
    #pragma unroll
    for (int r = 0; r < EPT; r++) {
        int i = base + r * BLK + t;
        if (i < NP) atomicAdd(&sh[key[i] & (RBUCK - 1)], 1);
    }
    __syncthreads();
    for (int d = t; d < RBUCK; d += BLK) hist[b * RBUCK + d] = sh[d];
}

// Histogram, passes 1..2 (u64 pairs, digit from high 32 bits).
__global__ void kv8_hist_p(const u64* __restrict__ pair, int* __restrict__ hist,
                           int NP, int shift) {
    __shared__ int sh[RBUCK];
    int t = threadIdx.x, b = blockIdx.x;
    for (int d = t; d < RBUCK; d += BLK) sh[d] = 0;
    __syncthreads();
    int base = b * ELEMS;
    #pragma unroll
    for (int r = 0; r < EPT; r++) {
        int i = base + r * BLK + t;
        if (i < NP) atomicAdd(&sh[(int)((pair[i] >> (32 + shift)) & (RBUCK - 1))], 1);
    }
    __syncthreads();
    for (int d = t; d < RBUCK; d += BLK) hist[b * RBUCK + d] = sh[d];
}

// Per-digit exclusive scan across blocks (grid = RBUCK; block d owns digit d).
__global__ void kv8_scanb(int* __restrict__ hist, int* __restrict__ dtot, int NB) {
    __shared__ int s[BLK];
    __shared__ int carry;
    int d = blockIdx.x, t = threadIdx.x;
    if (t == 0) carry = 0;
    __syncthreads();
    for (int base = 0; base < NB; base += BLK) {
        int b = base + t;
        int v = (b < NB) ? hist[b * RBUCK + d] : 0;
        s[t] = v; __syncthreads();
        for (int o = 1; o < BLK; o <<= 1) {
            int x = (t >= o) ? s[t - o] : 0; __syncthreads();
            s[t] += x; __syncthreads();
        }
        int incl = s[t], c = carry;
        if (b < NB) hist[b * RBUCK + d] = c + incl - v;
        __syncthreads();
        if (t == BLK - 1) carry = c + incl;
        __syncthreads();
    }
    if (t == 0) dtot[d] = carry;
}

// Exclusive scan of 512 digit totals.
__global__ void kv8_scand(const int* __restrict__ dtot, int* __restrict__ dbase) {
    __shared__ int s[RBUCK];
    int t = threadIdx.x;
    int v = dtot[t];
    s[t] = v;
    __syncthreads();
    for (int o = 1; o < RBUCK; o <<= 1) {
        int x = (t >= o) ? s[t - o] : 0; __syncthreads();
        s[t] += x; __syncthreads();
    }
    dbase[t] = s[t] - v;
}

// Stable scatter body: sub-batch-major order, ballot match intra-wave,
// whist cross-wave, cnt running across sub-batches. cnt pre-folds global base.
#define SCATTER_BODY(GET_KEY, GET_IDX)                                          \
    __shared__ int cnt[RBUCK];                                                  \
    __shared__ int whist[4][RBUCK];                                             \
    int t = threadIdx.x, b = blockIdx.x;                                        \
    int w = t >> 6, lane = t & 63;                                              \
    for (int d = t; d < RBUCK; d += BLK) cnt[d] = dbase[d] + hist[b * RBUCK + d]; \
    int base = b * ELEMS;                                                       \
    for (int r = 0; r < EPT; r++) {                                             \
        int i = base + r * BLK + t;                                             \
        bool act = i < NP;                                                      \
        int k = 0, idx = 0, d = 0;                                              \
        if (act) { GET_KEY; GET_IDX; d = (k >> shift) & (RBUCK - 1); }          \
        for (int x = t; x < 4 * RBUCK; x += BLK) ((int*)whist)[x] = 0;          \
        __syncthreads();                                                        \
        u64 m = __ballot(act);                                                  \
        _Pragma("unroll")                                                       \
        for (int bit = 0; bit < RBITS; bit++) {                                 \
            u64 bb = __ballot(act && ((d >> bit) & 1));                         \
            m &= ((d >> bit) & 1) ? bb : ~bb;                                   \
        }                                                                       \
        int rw = __popcll(m & ((1ull << lane) - 1ull));                         \
        if (act && rw == 0) whist[w][d] = __popcll(m);                          \
        __syncthreads();                                                        \
        if (act) {                                                              \
            int off = cnt[d];                                                   \
            for (int w2 = 0; w2 < w; w2++) off += whist[w2][d];                 \
            dpair[off + rw] = ((u64)(uint32_t)k << 32) | (uint32_t)idx;         \
        }                                                                       \
        __syncthreads();                                                        \
        for (int d2 = t; d2 < RBUCK; d2 += BLK) {                               \
            int ssum = 0;                                                       \
            _Pragma("unroll")                                                   \
            for (int w2 = 0; w2 < 4; w2++) ssum += whist[w2][d2];               \
            cnt[d2] += ssum;                                                    \
        }                                                                       \
        __syncthreads();                                                        \
    }

__global__ void kv8_scat0(const int* __restrict__ skey, u64* __restrict__ dpair,
                          const int* __restrict__ hist, const int* __restrict__ dbase,
                          int NP) {
    const int shift = 0;
    SCATTER_BODY(k = skey[i], idx = i)
}

__global__ void kv8_scatp(const u64* __restrict__ spair, u64* __restrict__ dpair,
                          const int* __restrict__ hist, const int* __restrict__ dbase,
                          int NP, int shift) {
    u64 pv;
    SCATTER_BODY(pv = spair[i]; k = (int)(pv >> 32), idx = (int)(pv & 0xFFFFFFFFull))
}

// Heads + valid flags -> per-block sums (thread-contiguous, vectorizable loads).
// Also zero-fills the byte-flag array (runs post-sort, pre-heads2).
__global__ void kv8_heads(const u64* __restrict__ pair, int* __restrict__ bsumH,
                          int* __restrict__ bsumV, const int* __restrict__ ctrl,
                          u64* __restrict__ flags8, int NP, int NP8) {
    __shared__ int sh[BLK], sv[BLK];
    int TOTAL = ctrl[2];
    int t = threadIdx.x, b = blockIdx.x;
    int gid = b * BLK + t;
    if (gid < NP8) flags8[gid] = 0ull;
    int sbase = b * ELEMS + t * EPT;
    int hs = 0, vs = 0;
    if (sbase < NP) {
        int kprev = (sbase == 0) ? -1 : (int)(pair[sbase - 1] >> 32);
        #pragma unroll
        for (int r = 0; r < EPT; r++) {
            int i = sbase + r;
            if (i < NP) {
                int k = (int)(pair[i] >> 32);
                if (k != TOTAL) { vs++; hs += (k != kprev); }
                kprev = k;
            }
        }
    }
    sh[t] = hs; sv[t] = vs;
    __syncthreads();
    for (int o = BLK / 2; o > 0; o >>= 1) {
        if (t < o) { sh[t] += sh[t + o]; sv[t] += sv[t + o]; }
        __syncthreads();
    }
    if (t == 0) { bsumH[b] = sh[0]; bsumV[b] = sv[0]; }
}

// Scan head block-sums in place; G -> ctrl[0], nvalid -> ctrl[1], voxel_num -> out.
__global__ void kv8_scanG(int* __restrict__ bsumH, const int* __restrict__ bsumV,
                          int NB, int* __restrict__ ctrl, float* __restrict__ out_vnum) {
    __shared__ int s[BLK];
    __shared__ int carry;
    int t = threadIdx.x;
    if (t == 0) carry = 0;
    __syncthreads();
    for (int base = 0; base < NB; base += BLK) {
        int b = base + t;
        int v = (b < NB) ? bsumH[b] : 0;
        s[t] = v; __syncthreads();
        for (int o = 1; o < BLK; o <<= 1) {
            int x = (t >= o) ? s[t - o] : 0; __syncthreads();
            s[t] += x; __syncthreads();
        }
        int incl = s[t], c = carry;
        if (b < NB) bsumH[b] = c + incl - v;
        __syncthreads();
        if (t == BLK - 1) carry = c + incl;
        __syncthreads();
    }
    if (t == 0) { ctrl[0] = carry; out_vnum[0] = (float)(carry < MAXV ? carry : MAXV); }
    __syncthreads();
    int acc = 0;
    for (int base = 0; base < NB; base += BLK) { int b = base + t; if (b < NB) acc += bsumV[b]; }
    s[t] = acc;
    __syncthreads();
    for (int o = BLK / 2; o > 0; o >>= 1) { if (t < o) s[t] += s[t + o]; __syncthreads(); }
    if (t == 0) ctrl[1] = s[0];
}

// Emit per-group records. Thread-contiguous chunks + ONE block scan; byte flags
// (no atomics — distinct byte addresses).
__global__ void kv8_heads2(const u64* __restrict__ pair, const int* __restrict__ bsumH,
                           int* __restrict__ gstart, int* __restrict__ ghead,
                           u64* __restrict__ flags8, const int* __restrict__ ctrl, int NP) {
    __shared__ int s[BLK];
    int TOTAL = ctrl[2];
    int t = threadIdx.x, b = blockIdx.x;
    int sbase = b * ELEMS + t * EPT;
    u64 pv[EPT];
    int hcnt = 0;
    unsigned hbits = 0;
    if (sbase < NP) {
        int kprev = (sbase == 0) ? -1 : (int)(pair[sbase - 1] >> 32);
        #pragma unroll
        for (int r = 0; r < EPT; r++) {
            int i = sbase + r;
            if (i < NP) {
                pv[r] = pair[i];
                int k = (int)(pv[r] >> 32);
                int h = (k != TOTAL) && (k != kprev);
                hbits |= (unsigned)h << r;
                hcnt += h;
                kprev = k;
            }
        }
    }
    s[t] = hcnt;
    __syncthreads();
    for (int o = 1; o < BLK; o <<= 1) {
        int x = (t >= o) ? s[t - o] : 0; __syncthreads();
        s[t] += x; __syncthreads();
    }
    if (sbase < NP && hbits) {
        int g = bsumH[b] + s[t] - hcnt;
        unsigned char* flags = (unsigned char*)flags8;
        #pragma unroll
        for (int r = 0; r < EPT; r++) {
            if ((hbits >> r) & 1) {
                gstart[g] = sbase + r;
                int io = (int)(pv[r] & 0xFFFFFFFFull);
                ghead[g] = io;
                flags[io] = 1;
                g++;
            }
        }
    }
}

// wpfx 3-phase scan over byte-flag words (bytesum via multiply trick).
__global__ void kv8_wpA(const u64* __restrict__ flags8, int* __restrict__ wsum, int NP8) {
    __shared__ int s[BLK];
    int t = threadIdx.x, i = blockIdx.x * BLK + t;
    u64 wv = (i < NP8) ? flags8[i] : 0ull;
    s[t] = (int)((wv * BYTEMUL) >> 56);
    __syncthreads();
    for (int o = BLK / 2; o > 0; o >>= 1) { if (t < o) s[t] += s[t + o]; __syncthreads(); }
    if (t == 0) wsum[blockIdx.x] = s[0];
}
__global__ void kv8_wpB(int* __restrict__ wsum, int nws) {
    __shared__ int s[BLK];
    __shared__ int carry;
    int t = threadIdx.x;
    if (t == 0) carry = 0;
    __syncthreads();
    for (int base = 0; base < nws; base += BLK) {
        int i = base + t;
        int v = (i < nws) ? wsum[i] : 0;
        s[t] = v; __syncthreads();
        for (int o = 1; o < BLK; o <<= 1) {
            int x = (t >= o) ? s[t - o] : 0; __syncthreads();
            s[t] += x; __syncthreads();
        }
        int incl = s[t], c = carry;
        if (i < nws) wsum[i] = c + incl - v;
        __syncthreads();
        if (t == BLK - 1) carry = c + incl;
        __syncthreads();
    }
}
__global__ void kv8_wpC(const u64* __restrict__ flags8, const int* __restrict__ wsum,
                        int* __restrict__ wpfx, int NP8) {
    __shared__ int s[BLK];
    int t = threadIdx.x, i = blockIdx.x * BLK + t;
    u64 wv = (i < NP8) ? flags8[i] : 0ull;
    int v = (int)((wv * BYTEMUL) >> 56);
    s[t] = v;
    __syncthreads();
    for (int o = 1; o < BLK; o <<= 1) {
        int x = (t >= o) ? s[t - o] : 0; __syncthreads();
        s[t] += x; __syncthreads();
    }
    if (i < NP8) wpfx[i] = wsum[blockIdx.x] + s[t] - v;
}

// Zero-fill voxels + coors + npv (out is poisoned before every timed replay).
__global__ void kv8_zero(float4* __restrict__ out4, int n4) {
    int i = blockIdx.x * BLK + threadIdx.x;
    if (i < n4) out4[i] = make_float4(0.f, 0.f, 0.f, 0.f);
}

__device__ __forceinline__ int vox_rank(const u64* flags8, const int* wpfx, int io) {
    int w = io >> 3, b8 = io & 7;
    u64 below = flags8[w] & ((1ull << (8 * b8)) - 1ull);   // b8=0 -> 0
    return wpfx[w] + (int)((below * BYTEMUL) >> 56);
}

// Per-voxel outputs: coors (z,y,x) + clamped counts.
__global__ void kv8_pervox(const int* __restrict__ gstart, const int* __restrict__ ghead,
                           const u64* __restrict__ pair, const u64* __restrict__ flags8,
                           const int* __restrict__ wpfx, const int* __restrict__ ctrl,
                           const float* __restrict__ vsz, const float* __restrict__ crg,
                           float* __restrict__ out) {
    int g = blockIdx.x * BLK + threadIdx.x;
    int G = ctrl[0], nval = ctrl[1];
    if (g >= G) return;
    int io = ghead[g];
    int vid = vox_rank(flags8, wpfx, io);
    if (vid >= MAXV) return;
    int p0 = gstart[g];
    int k = (int)(pair[p0] >> 32);
    int gy = (int)rintf((crg[4] - crg[1]) / vsz[1]);
    int gz = (int)rintf((crg[5] - crg[2]) / vsz[2]);
    int cz = k % gz; int rr = k / gz; int cy = rr % gy; int cx = rr / gy;
    out[CO_OFF + vid * 3 + 0] = (float)cz;
    out[CO_OFF + vid * 3 + 1] = (float)cy;
    out[CO_OFF + vid * 3 + 2] = (float)cx;
    int gsz = ((g + 1 < G) ? gstart[g + 1] : nval) - p0;
    out[NPV_OFF + vid] = (float)(gsz < MAXP ? gsz : MAXP);
}

// Emit voxel point payloads.
__global__ void kv8_emit(const u64* __restrict__ pair, const int* __restrict__ gstart,
                         const int* __restrict__ ghead, const u64* __restrict__ flags8,
                         const int* __restrict__ wpfx, const int* __restrict__ ctrl,
                         const float* __restrict__ pts, float* __restrict__ out, int NP) {
    int p = blockIdx.x * BLK + threadIdx.x;
    if (p >= NP) return;
    int TOTAL = ctrl[2], G = ctrl[0];
    u64 pv = pair[p];
    int k = (int)(pv >> 32);
    if (k == TOTAL) return;                 // invalids sorted to the end
    int lo = 0, hi = G - 1;                 // G >= 1 here (a valid element exists)
    while (lo < hi) {                       // largest g with gstart[g] <= p
        int mid = (lo + hi + 1) >> 1;
        if (gstart[mid] <= p) lo = mid; else hi = mid - 1;
    }
    int g = lo;
    int slot = p - gstart[g];
    if (slot >= MAXP) return;
    int vid = vox_rank(flags8, wpfx, ghead[g]);
    if (vid >= MAXV) return;
    int iorig = (int)(pv & 0xFFFFFFFFull);
    const float* src = pts + iorig * C;
    float* dst = out + (vid * MAXP + slot) * C;
    dst[0] = src[0]; dst[1] = src[1]; dst[2] = src[2]; dst[3] = src[3]; dst[4] = src[4];
}

extern "C" void kernel_launch(void* const* d_in, const int* in_sizes, int n_in,
                              void* d_out, int out_size, void* d_ws, size_t ws_size,
                              hipStream_t stream) {
    if (!d_out || !d_ws || n_in < 3) return;
    const float* pts = (const float*)d_in[0];
    const float* vsz = (const float*)d_in[1];
    const float* crg = (const float*)d_in[2];
    if (!pts || !vsz || !crg) return;
    const int NP  = in_sizes[0] / C;
    if (NP <= 0) return;
    const int NB  = (NP + ELEMS - 1) / ELEMS;     // sort/heads blocks (586)
    const int NBS = (NP + BLK - 1) / BLK;         // per-point kernels (4688)
    const int NP8 = (NP + 7) / 8;                 // byte-flag u64 words (146485)
    const int NW8 = (NP8 + BLK - 1) / BLK;        // wpfx blocks (573)

    // Workspace budget (bytes); flags8 aliases hist (RBUCK*NB*4 >= NP8*8 always,
    // since 2048*ceil(NP/2048) >= 8*ceil(NP/8)).
    size_t need = 2ull * NP * 8ull                       // pairA + pairB (key0 aliases pairB)
                + (size_t)RBUCK * NB * 4ull              // hist / flags8
                + 2ull * NB * 4ull                       // bsumH, bsumV
                + 2ull * RBUCK * 4ull                    // dtot, dbase
                + (size_t)NP8 * 4ull                     // wpfx
                + (size_t)NW8 * 4ull + 8ull * 4ull + 16ull; // wsum, ctrl, align pad
    if (ws_size < need) return;
    if ((size_t)out_size < (size_t)VN_OFF + 1) return;

    u64* pairA = (u64*)d_ws;
    u64* pairB = pairA + NP;
    int* key0  = (int*)pairB;                     // aliases pairB (dead before pass 1 writes)
    int* w     = (int*)(pairB + NP);
    int* hist  = w; w += (size_t)RBUCK * NB;
    u64* flags8 = (u64*)hist;                     // aliases hist (dead after last scatter)
    int* bsumH = w; w += NB;
    int* bsumV = w; w += NB;
    int* dtot  = w; w += RBUCK;
    int* dbase = w; w += RBUCK;
    int* wpfx  = w; w += NP8;
    int* wsum  = w; w += NW8;
    int* ctrl  = w; w += 8;

    float* out = (float*)d_out;

    kv8_lin<<<NBS, BLK, 0, stream>>>(pts, vsz, crg, key0, ctrl, NP);
    kv8_zero<<<(VN_OFF / 4 + BLK - 1) / BLK, BLK, 0, stream>>>((float4*)out, VN_OFF / 4);

    // Pass 0: key0 (int) -> pairA
    kv8_hist_i<<<NB, BLK, 0, stream>>>(key0, hist, NP);
    kv8_scanb<<<RBUCK, BLK, 0, stream>>>(hist, dtot, NB);
    kv8_scand<<<1, RBUCK, 0, stream>>>(dtot, dbase);
    kv8_scat0<<<NB, BLK, 0, stream>>>(key0, pairA, hist, dbase, NP);
    // Pass 1: pairA -> pairB (clobbers key0 — dead)
    kv8_hist_p<<<NB, BLK, 0, stream>>>(pairA, hist, NP, RBITS);
    kv8_scanb<<<RBUCK, BLK, 0, stream>>>(hist, dtot, NB);
    kv8_scand<<<1, RBUCK, 0, stream>>>(dtot, dbase);
    kv8_scatp<<<NB, BLK, 0, stream>>>(pairA, pairB, hist, dbase, NP, RBITS);
    // Pass 2: pairB -> pairA (final sorted order)
    kv8_hist_p<<<NB, BLK, 0, stream>>>(pairB, hist, NP, 2 * RBITS);
    kv8_scanb<<<RBUCK, BLK, 0, stream>>>(hist, dtot, NB);
    kv8_scand<<<1, RBUCK, 0, stream>>>(dtot, dbase);
    kv8_scatp<<<NB, BLK, 0, stream>>>(pairB, pairA, hist, dbase, NP, 2 * RBITS);

    int* gstart = (int*)pairB;                    // pairB free after pass 2
    int* ghead  = gstart + NP;

    kv8_heads<<<NB, BLK, 0, stream>>>(pairA, bsumH, bsumV, ctrl, flags8, NP, NP8);
    kv8_scanG<<<1, BLK, 0, stream>>>(bsumH, bsumV, NB, ctrl, out + VN_OFF);
    kv8_heads2<<<NB, BLK, 0, stream>>>(pairA, bsumH, gstart, ghead, flags8, ctrl, NP);
    kv8_wpA<<<NW8, BLK, 0, stream>>>(flags8, wsum, NP8);
    kv8_wpB<<<1, BLK, 0, stream>>>(wsum, NW8);
    kv8_wpC<<<NW8, BLK, 0, stream>>>(flags8, wsum, wpfx, NP8);
    kv8_pervox<<<NBS, BLK, 0, stream>>>(gstart, ghead, pairA, flags8, wpfx, ctrl, vsz, crg, out);
    kv8_emit<<<NBS, BLK, 0, stream>>>(pairA, gstart, ghead, flags8, wpfx, ctrl, pts, out, NP);
}

// Round 9
// 247.025 us; speedup vs baseline: 428.9487x; 1.1373x over previous
//
#include <hip/hip_runtime.h>
#include <cstdint>

static constexpr int C     = 5;
static constexpr int MAXP  = 10;
static constexpr int MAXV  = 160000;
static constexpr int BLK   = 256;
static constexpr int RBITS = 9;
static constexpr int RBUCK = 1 << RBITS;   // 512 buckets
static constexpr int EPT   = 8;            // elements per thread
static constexpr int ELEMS = BLK * EPT;    // 2048 elements per block

// Output layout (float32, concatenated in reference return order)
static constexpr int VOX_OFF = 0;                           // 160000*10*5
static constexpr int CO_OFF  = MAXV * MAXP * C;             // 8,000,000
static constexpr int NPV_OFF = CO_OFF + MAXV * 3;           // 8,480,000
static constexpr int VN_OFF  = NPV_OFF + MAXV;              // 8,640,000

typedef unsigned long long u64;
static constexpr u64 BYTEMUL = 0x0101010101010101ull;

// K1: quantize -> int keys AND pass-0 block histogram (fused).
__global__ void kv9_linhist(const float* __restrict__ pts, const float* __restrict__ vsz,
                            const float* __restrict__ crg, int* __restrict__ key0,
                            int* __restrict__ hist, int* __restrict__ ctrl, int NP) {
    __shared__ int sh[RBUCK];
    int t = threadIdx.x, b = blockIdx.x;
    for (int d = t; d < RBUCK; d += BLK) sh[d] = 0;
    float vx = vsz[0], vy = vsz[1], vz = vsz[2];
    float x0 = crg[0], y0 = crg[1], z0 = crg[2];
    int gx = (int)rintf((crg[3] - x0) / vx);
    int gy = (int)rintf((crg[4] - y0) / vy);
    int gz = (int)rintf((crg[5] - z0) / vz);
    int total = gx * gy * gz;
    if (b == 0 && t == 0) ctrl[2] = total;
    __syncthreads();
    int base = b * ELEMS;
    #pragma unroll
    for (int r = 0; r < EPT; r++) {
        int i = base + r * BLK + t;
        if (i < NP) {
            float px = pts[i * C], py = pts[i * C + 1], pz = pts[i * C + 2];
            int cx = (int)floorf((px - x0) / vx);
            int cy = (int)floorf((py - y0) / vy);
            int cz = (int)floorf((pz - z0) / vz);
            bool valid = (cx >= 0) & (cx < gx) & (cy >= 0) & (cy < gy) & (cz >= 0) & (cz < gz);
            int k = valid ? (cx * gy + cy) * gz + cz : total;
            key0[i] = k;
            atomicAdd(&sh[k & (RBUCK - 1)], 1);
        }
    }
    __syncthreads();
    for (int d = t; d < RBUCK; d += BLK) hist[b * RBUCK + d] = sh[d];
}

// Histogram, passes 1..2 (u64 pairs, digit from high 32 bits).
__global__ void kv9_hist_p(const u64* __restrict__ pair, int* __restrict__ hist,
                           int NP, int shift) {
    __shared__ int sh[RBUCK];
    int t = threadIdx.x, b = blockIdx.x;
    for (int d = t; d < RBUCK; d += BLK) sh[d] = 0;
    __syncthreads();
    int base = b * ELEMS;
    #pragma unroll
    for (int r = 0; r < EPT; r++) {
        int i = base + r * BLK + t;
        if (i < NP) atomicAdd(&sh[(int)((pair[i] >> (32 + shift)) & (RBUCK - 1))], 1);
    }
    __syncthreads();
    for (int d = t; d < RBUCK; d += BLK) hist[b * RBUCK + d] = sh[d];
}

// Per-digit exclusive scan across blocks (grid = RBUCK; block d owns digit d).
__global__ void kv9_scanb(int* __restrict__ hist, int* __restrict__ dtot, int NB) {
    __shared__ int s[BLK];
    __shared__ int carry;
    int d = blockIdx.x, t = threadIdx.x;
    if (t == 0) carry = 0;
    __syncthreads();
    for (int base = 0; base < NB; base += BLK) {
        int b = base + t;
        int v = (b < NB) ? hist[b * RBUCK + d] : 0;
        s[t] = v; __syncthreads();
        for (int o = 1; o < BLK; o <<= 1) {
            int x = (t >= o) ? s[t - o] : 0; __syncthreads();
            s[t] += x; __syncthreads();
        }
        int incl = s[t], c = carry;
        if (b < NB) hist[b * RBUCK + d] = c + incl - v;
        __syncthreads();
        if (t == BLK - 1) carry = c + incl;
        __syncthreads();
    }
    if (t == 0) dtot[d] = carry;
}

// Stable scatter. dbase computed in-block (wave-0 scan of dtot, 1 sync).
// Round-tagged whist (no zeroing); 2 syncs per sub-batch round.
#define SCAT9_BODY(GET_KEY, GET_IDX)                                            \
    __shared__ int cnt[RBUCK];                                                  \
    __shared__ int dbS[RBUCK];                                                  \
    __shared__ int whist[4][RBUCK];                                             \
    int t = threadIdx.x, b = blockIdx.x;                                        \
    int w = t >> 6, lane = t & 63;                                              \
    if (t < 64) {                                                               \
        int loc[8]; int run = 0;                                                \
        _Pragma("unroll")                                                       \
        for (int j = 0; j < 8; j++) { loc[j] = run; run += dtot[t * 8 + j]; }   \
        int tot = run;                                                          \
        for (int o = 1; o < 64; o <<= 1) {                                      \
            int x = __shfl_up(tot, o, 64);                                      \
            if (lane >= o) tot += x;                                            \
        }                                                                       \
        int excl = tot - run;                                                   \
        _Pragma("unroll")                                                       \
        for (int j = 0; j < 8; j++) dbS[t * 8 + j] = excl + loc[j];             \
    }                                                                           \
    for (int x = t; x < 4 * RBUCK; x += BLK) ((int*)whist)[x] = -1;             \
    __syncthreads();                                                            \
    for (int d = t; d < RBUCK; d += BLK) cnt[d] = dbS[d] + hist[b * RBUCK + d]; \
    __syncthreads();                                                            \
    int base = b * ELEMS;                                                       \
    int nc0 = 0, nc1 = 0; bool havenc = false;                                  \
    for (int r = 0; r < EPT; r++) {                                             \
        int i = base + r * BLK + t;                                             \
        bool act = i < NP;                                                      \
        int k = 0, idx = 0, d = 0;                                              \
        if (act) { GET_KEY; GET_IDX; d = (k >> shift) & (RBUCK - 1); }          \
        u64 m = __ballot(act);                                                  \
        _Pragma("unroll")                                                       \
        for (int bit = 0; bit < RBITS; bit++) {                                 \
            u64 bb = __ballot(act && ((d >> bit) & 1));                         \
            m &= ((d >> bit) & 1) ? bb : ~bb;                                   \
        }                                                                       \
        int rw = __popcll(m & ((1ull << lane) - 1ull));                         \
        /* phase W: write back prev round's cnt; publish this round's whist */  \
        if (havenc) { cnt[t] = nc0; cnt[t + BLK] = nc1; }                       \
        if (act && rw == 0) whist[w][d] = (r << 20) | (int)__popcll(m);         \
        __syncthreads();                                                        \
        /* phase R: read cnt+whist, scatter, precompute next cnt */             \
        if (act) {                                                              \
            int off = cnt[d];                                                   \
            for (int w2 = 0; w2 < w; w2++) {                                    \
                int e = whist[w2][d];                                           \
                off += ((e >> 20) == r) ? (e & 0xFFFFF) : 0;                    \
            }                                                                   \
            dpair[off + rw] = ((u64)(uint32_t)k << 32) | (uint32_t)idx;         \
        }                                                                       \
        {                                                                       \
            int s0 = 0, s1 = 0;                                                 \
            _Pragma("unroll")                                                   \
            for (int w2 = 0; w2 < 4; w2++) {                                    \
                int e0 = whist[w2][t];                                          \
                int e1 = whist[w2][t + BLK];                                    \
                s0 += ((e0 >> 20) == r) ? (e0 & 0xFFFFF) : 0;                   \
                s1 += ((e1 >> 20) == r) ? (e1 & 0xFFFFF) : 0;                   \
            }                                                                   \
            nc0 = cnt[t] + s0; nc1 = cnt[t + BLK] + s1; havenc = true;          \
        }                                                                       \
        __syncthreads();                                                        \
    }

__global__ void kv9_scat0(const int* __restrict__ skey, u64* __restrict__ dpair,
                          const int* __restrict__ hist, const int* __restrict__ dtot,
                          int NP) {
    const int shift = 0;
    SCAT9_BODY(k = skey[i], idx = i)
}

__global__ void kv9_scatp(const u64* __restrict__ spair, u64* __restrict__ dpair,
                          const int* __restrict__ hist, const int* __restrict__ dtot,
                          int NP, int shift) {
    u64 pv;
    SCAT9_BODY(pv = spair[i]; k = (int)(pv >> 32), idx = (int)(pv & 0xFFFFFFFFull))
}

// Heads + valid flags -> per-block sums; zero-fills byte-flag array.
__global__ void kv9_heads(const u64* __restrict__ pair, int* __restrict__ bsumH,
                          int* __restrict__ bsumV, const int* __restrict__ ctrl,
                          u64* __restrict__ flags8, int NP, int NP8) {
    __shared__ int sh[BLK], sv[BLK];
    int TOTAL = ctrl[2];
    int t = threadIdx.x, b = blockIdx.x;
    int gid = b * BLK + t;
    if (gid < NP8) flags8[gid] = 0ull;
    int sbase = b * ELEMS + t * EPT;
    int hs = 0, vs = 0;
    if (sbase < NP) {
        int kprev = (sbase == 0) ? -1 : (int)(pair[sbase - 1] >> 32);
        #pragma unroll
        for (int r = 0; r < EPT; r++) {
            int i = sbase + r;
            if (i < NP) {
                int k = (int)(pair[i] >> 32);
                if (k != TOTAL) { vs++; hs += (k != kprev); }
                kprev = k;
            }
        }
    }
    sh[t] = hs; sv[t] = vs;
    __syncthreads();
    for (int o = BLK / 2; o > 0; o >>= 1) {
        if (t < o) { sh[t] += sh[t + o]; sv[t] += sv[t + o]; }
        __syncthreads();
    }
    if (t == 0) { bsumH[b] = sh[0]; bsumV[b] = sv[0]; }
}

// Scan head block-sums in place; G -> ctrl[0], nvalid -> ctrl[1], voxel_num -> out.
__global__ void kv9_scanG(int* __restrict__ bsumH, const int* __restrict__ bsumV,
                          int NB, int* __restrict__ ctrl, float* __restrict__ out_vnum) {
    __shared__ int s[BLK];
    __shared__ int carry;
    int t = threadIdx.x;
    if (t == 0) carry = 0;
    __syncthreads();
    for (int base = 0; base < NB; base += BLK) {
        int b = base + t;
        int v = (b < NB) ? bsumH[b] : 0;
        s[t] = v; __syncthreads();
        for (int o = 1; o < BLK; o <<= 1) {
            int x = (t >= o) ? s[t - o] : 0; __syncthreads();
            s[t] += x; __syncthreads();
        }
        int incl = s[t], c = carry;
        if (b < NB) bsumH[b] = c + incl - v;
        __syncthreads();
        if (t == BLK - 1) carry = c + incl;
        __syncthreads();
    }
    if (t == 0) { ctrl[0] = carry; out_vnum[0] = (float)(carry < MAXV ? carry : MAXV); }
    __syncthreads();
    int acc = 0;
    for (int base = 0; base < NB; base += BLK) { int b = base + t; if (b < NB) acc += bsumV[b]; }
    s[t] = acc;
    __syncthreads();
    for (int o = BLK / 2; o > 0; o >>= 1) { if (t < o) s[t] += s[t + o]; __syncthreads(); }
    if (t == 0) ctrl[1] = s[0];
}

// Emit per-group records (gstart, ghead, byte flag). One block scan; no atomics.
__global__ void kv9_heads2(const u64* __restrict__ pair, const int* __restrict__ bsumH,
                           int* __restrict__ gstart, int* __restrict__ ghead,
                           u64* __restrict__ flags8, const int* __restrict__ ctrl, int NP) {
    __shared__ int s[BLK];
    int TOTAL = ctrl[2];
    int t = threadIdx.x, b = blockIdx.x;
    int sbase = b * ELEMS + t * EPT;
    u64 pv[EPT];
    int hcnt = 0;
    unsigned hbits = 0;
    if (sbase < NP) {
        int kprev = (sbase == 0) ? -1 : (int)(pair[sbase - 1] >> 32);
        #pragma unroll
        for (int r = 0; r < EPT; r++) {
            int i = sbase + r;
            if (i < NP) {
                pv[r] = pair[i];
                int k = (int)(pv[r] >> 32);
                int h = (k != TOTAL) && (k != kprev);
                hbits |= (unsigned)h << r;
                hcnt += h;
                kprev = k;
            }
        }
    }
    s[t] = hcnt;
    __syncthreads();
    for (int o = 1; o < BLK; o <<= 1) {
        int x = (t >= o) ? s[t - o] : 0; __syncthreads();
        s[t] += x; __syncthreads();
    }
    if (sbase < NP && hbits) {
        int g = bsumH[b] + s[t] - hcnt;
        unsigned char* flags = (unsigned char*)flags8;
        #pragma unroll
        for (int r = 0; r < EPT; r++) {
            if ((hbits >> r) & 1) {
                gstart[g] = sbase + r;
                int io = (int)(pv[r] & 0xFFFFFFFFull);
                ghead[g] = io;
                flags[io] = 1;
                g++;
            }
        }
    }
}

// wpfx 3-phase scan over byte-flag words (bytesum via multiply trick).
__global__ void kv9_wpA(const u64* __restrict__ flags8, int* __restrict__ wsum, int NP8) {
    __shared__ int s[BLK];
    int t = threadIdx.x, i = blockIdx.x * BLK + t;
    u64 wv = (i < NP8) ? flags8[i] : 0ull;
    s[t] = (int)((wv * BYTEMUL) >> 56);
    __syncthreads();
    for (int o = BLK / 2; o > 0; o >>= 1) { if (t < o) s[t] += s[t + o]; __syncthreads(); }
    if (t == 0) wsum[blockIdx.x] = s[0];
}
__global__ void kv9_wpB(int* __restrict__ wsum, int nws) {
    __shared__ int s[BLK];
    __shared__ int carry;
    int t = threadIdx.x;
    if (t == 0) carry = 0;
    __syncthreads();
    for (int base = 0; base < nws; base += BLK) {
        int i = base + t;
        int v = (i < nws) ? wsum[i] : 0;
        s[t] = v; __syncthreads();
        for (int o = 1; o < BLK; o <<= 1) {
            int x = (t >= o) ? s[t - o] : 0; __syncthreads();
            s[t] += x; __syncthreads();
        }
        int incl = s[t], c = carry;
        if (i < nws) wsum[i] = c + incl - v;
        __syncthreads();
        if (t == BLK - 1) carry = c + incl;
        __syncthreads();
    }
}
__global__ void kv9_wpC(const u64* __restrict__ flags8, const int* __restrict__ wsum,
                        int* __restrict__ wpfx, int NP8) {
    __shared__ int s[BLK];
    int t = threadIdx.x, i = blockIdx.x * BLK + t;
    u64 wv = (i < NP8) ? flags8[i] : 0ull;
    int v = (int)((wv * BYTEMUL) >> 56);
    s[t] = v;
    __syncthreads();
    for (int o = 1; o < BLK; o <<= 1) {
        int x = (t >= o) ? s[t - o] : 0; __syncthreads();
        s[t] += x; __syncthreads();
    }
    if (i < NP8) wpfx[i] = wsum[blockIdx.x] + s[t] - v;
}

// Zero-fill voxels + coors + npv.
__global__ void kv9_zero(float4* __restrict__ out4, int n4) {
    int i = blockIdx.x * BLK + threadIdx.x;
    if (i < n4) out4[i] = make_float4(0.f, 0.f, 0.f, 0.f);
}

__device__ __forceinline__ int vox_rank(const u64* flags8, const int* wpfx, int io) {
    int w = io >> 3, b8 = io & 7;
    u64 below = flags8[w] & ((1ull << (8 * b8)) - 1ull);
    return wpfx[w] + (int)((below * BYTEMUL) >> 56);
}

// Fused emit: per-element group id via block scan + bsumH (no binary search);
// heads also write coors/npv (former pervox).
__global__ void kv9_emit(const u64* __restrict__ pair, const int* __restrict__ gstart,
                         const int* __restrict__ ghead, const u64* __restrict__ flags8,
                         const int* __restrict__ wpfx, const int* __restrict__ ctrl,
                         const int* __restrict__ bsumH, const float* __restrict__ pts,
                         const float* __restrict__ vsz, const float* __restrict__ crg,
                         float* __restrict__ out, int NP) {
    __shared__ int s[BLK];
    int TOTAL = ctrl[2], G = ctrl[0], nval = ctrl[1];
    int t = threadIdx.x, b = blockIdx.x;
    int sbase = b * ELEMS + t * EPT;
    u64 pv[EPT];
    int hcnt = 0;
    unsigned hbits = 0;
    if (sbase < NP) {
        int kprev = (sbase == 0) ? -1 : (int)(pair[sbase - 1] >> 32);
        #pragma unroll
        for (int r = 0; r < EPT; r++) {
            int i = sbase + r;
            if (i < NP) {
                pv[r] = pair[i];
                int k = (int)(pv[r] >> 32);
                int h = (k != TOTAL) && (k != kprev);
                hbits |= (unsigned)h << r;
                hcnt += h;
                kprev = k;
            }
        }
    }
    s[t] = hcnt;
    __syncthreads();
    for (int o = 1; o < BLK; o <<= 1) {
        int x = (t >= o) ? s[t - o] : 0; __syncthreads();
        s[t] += x; __syncthreads();
    }
    if (sbase >= NP) return;
    int gg = bsumH[b] + (s[t] - hcnt) - 1;   // group of element BEFORE this chunk
    int gyd = (int)rintf((crg[4] - crg[1]) / vsz[1]);
    int gzd = (int)rintf((crg[5] - crg[2]) / vsz[2]);
    #pragma unroll
    for (int r = 0; r < EPT; r++) {
        int i = sbase + r;
        if (i >= NP) break;
        int h = (hbits >> r) & 1;
        gg += h;
        u64 p = pv[r];
        int k = (int)(p >> 32);
        if (k == TOTAL) continue;            // sorted suffix of invalids
        int p0 = gstart[gg];
        int vid = vox_rank(flags8, wpfx, ghead[gg]);
        if (vid >= MAXV) continue;
        if (h) {                             // pervox work (once per group)
            int cz = k % gzd; int rr = k / gzd; int cy = rr % gyd; int cx = rr / gyd;
            out[CO_OFF + vid * 3 + 0] = (float)cz;
            out[CO_OFF + vid * 3 + 1] = (float)cy;
            out[CO_OFF + vid * 3 + 2] = (float)cx;
            int nxt = (gg + 1 < G) ? gstart[gg + 1] : nval;
            int gsz = nxt - p0;
            out[NPV_OFF + vid] = (float)(gsz < MAXP ? gsz : MAXP);
        }
        int slot = i - p0;
        if (slot >= MAXP) continue;
        int iorig = (int)(p & 0xFFFFFFFFull);
        const float* src = pts + iorig * C;
        float* dst = out + (vid * MAXP + slot) * C;
        dst[0] = src[0]; dst[1] = src[1]; dst[2] = src[2]; dst[3] = src[3]; dst[4] = src[4];
    }
}

extern "C" void kernel_launch(void* const* d_in, const int* in_sizes, int n_in,
                              void* d_out, int out_size, void* d_ws, size_t ws_size,
                              hipStream_t stream) {
    if (!d_out || !d_ws || n_in < 3) return;
    const float* pts = (const float*)d_in[0];
    const float* vsz = (const float*)d_in[1];
    const float* crg = (const float*)d_in[2];
    if (!pts || !vsz || !crg) return;
    const int NP  = in_sizes[0] / C;
    if (NP <= 0) return;
    const int NB  = (NP + ELEMS - 1) / ELEMS;     // 2048-elem blocks (586)
    const int NP8 = (NP + 7) / 8;                 // byte-flag u64 words (150000)
    const int NW8 = (NP8 + BLK - 1) / BLK;        // wpfx blocks (586)

    // Workspace budget (bytes); flags8 aliases hist (RBUCK*NB*4 >= NP8*8 always).
    size_t need = 2ull * NP * 8ull                          // pairA + pairB
                + (size_t)RBUCK * NB * 4ull                 // hist / flags8
                + 2ull * NB * 4ull                          // bsumH, bsumV
                + (size_t)RBUCK * 4ull                      // dtot
                + (size_t)NP8 * 4ull                        // wpfx
                + (size_t)NW8 * 4ull + 8ull * 4ull + 16ull; // wsum, ctrl, pad
    if (ws_size < need) return;
    if ((size_t)out_size < (size_t)VN_OFF + 1) return;

    u64* pairA = (u64*)d_ws;
    u64* pairB = pairA + NP;
    int* key0  = (int*)pairB;                     // aliases pairB (dead before pass 1 writes)
    int* w     = (int*)(pairB + NP);
    int* hist  = w; w += (size_t)RBUCK * NB;
    u64* flags8 = (u64*)hist;                     // aliases hist (dead after last scatter)
    int* bsumH = w; w += NB;
    int* bsumV = w; w += NB;
    int* dtot  = w; w += RBUCK;
    int* wpfx  = w; w += NP8;
    int* wsum  = w; w += NW8;
    int* ctrl  = w; w += 8;

    float* out = (float*)d_out;

    kv9_linhist<<<NB, BLK, 0, stream>>>(pts, vsz, crg, key0, hist, ctrl, NP);
    kv9_zero<<<(VN_OFF / 4 + BLK - 1) / BLK, BLK, 0, stream>>>((float4*)out, VN_OFF / 4);

    // Pass 0: key0 (int) -> pairA
    kv9_scanb<<<RBUCK, BLK, 0, stream>>>(hist, dtot, NB);
    kv9_scat0<<<NB, BLK, 0, stream>>>(key0, pairA, hist, dtot, NP);
    // Pass 1: pairA -> pairB (clobbers key0 — dead)
    kv9_hist_p<<<NB, BLK, 0, stream>>>(pairA, hist, NP, RBITS);
    kv9_scanb<<<RBUCK, BLK, 0, stream>>>(hist, dtot, NB);
    kv9_scatp<<<NB, BLK, 0, stream>>>(pairA, pairB, hist, dtot, NP, RBITS);
    // Pass 2: pairB -> pairA (final sorted order)
    kv9_hist_p<<<NB, BLK, 0, stream>>>(pairB, hist, NP, 2 * RBITS);
    kv9_scanb<<<RBUCK, BLK, 0, stream>>>(hist, dtot, NB);
    kv9_scatp<<<NB, BLK, 0, stream>>>(pairB, pairA, hist, dtot, NP, 2 * RBITS);

    int* gstart = (int*)pairB;                    // pairB free after pass 2
    int* ghead  = gstart + NP;

    kv9_heads<<<NB, BLK, 0, stream>>>(pairA, bsumH, bsumV, ctrl, flags8, NP, NP8);
    kv9_scanG<<<1, BLK, 0, stream>>>(bsumH, bsumV, NB, ctrl, out + VN_OFF);
    kv9_heads2<<<NB, BLK, 0, stream>>>(pairA, bsumH, gstart, ghead, flags8, ctrl, NP);
    kv9_wpA<<<NW8, BLK, 0, stream>>>(flags8, wsum, NP8);
    kv9_wpB<<<1, BLK, 0, stream>>>(wsum, NW8);
    kv9_wpC<<<NW8, BLK, 0, stream>>>(flags8, wsum, wpfx, NP8);
    kv9_emit<<<NB, BLK, 0, stream>>>(pairA, gstart, ghead, flags8, wpfx, ctrl,
                                     bsumH, pts, vsz, crg, out, NP);
}